// Round 8
// baseline (220.696 us; speedup 1.0000x reference)
//
#include <hip/hip_runtime.h>
#include <math.h>

#define NN   24          // nodes per graph
#define EPB  16          // graph elements per block
#define CSTR 28          // LDS column stride (floats): 24 + 4 pad, 16B aligned
#define ESTR 452         // per-elem stride: 16*28 + 4 → e-stride ≡ 4 banks mod 32
#define T    256
#define AT_OFF 2176      // A^T (24x24) in ws, 16B-aligned float offset

typedef float v2f __attribute__((ext_vector_type(2)));
typedef float v4f __attribute__((ext_vector_type(4)));

// Guaranteed packed math: d = a*b + c on 2xf32 register pairs.
static __device__ __forceinline__ v2f pkfma(v2f a, v2f b, v2f c) {
  asm("v_pk_fma_f32 %0, %1, %2, %0" : "+v"(c) : "v"(a), "v"(b));
  return c;
}
// c += a * broadcast(b.lo)  (src1 low half replicated via op_sel — no splat mov)
static __device__ __forceinline__ v2f pkfma_b0(v2f a, v2f b, v2f c) {
  asm("v_pk_fma_f32 %0, %1, %2, %0 op_sel:[0,0,0] op_sel_hi:[1,0,1]"
      : "+v"(c) : "v"(a), "v"(b));
  return c;
}
// c += a * broadcast(b.hi)
static __device__ __forceinline__ v2f pkfma_b1(v2f a, v2f b, v2f c) {
  asm("v_pk_fma_f32 %0, %1, %2, %0 op_sel:[0,1,0] op_sel_hi:[1,1,1]"
      : "+v"(c) : "v"(a), "v"(b));
  return c;
}
// Same, but a (src0) delivered from an SGPR pair — scalar-pipe operand flow.
// VOP3P allows one SGPR operand; avoids both LDS traffic and s->v movs.
static __device__ __forceinline__ v2f pkfma_sb0(v2f a, v2f b, v2f c) {
  asm("v_pk_fma_f32 %0, %1, %2, %0 op_sel:[0,0,0] op_sel_hi:[1,0,1]"
      : "+v"(c) : "s"(a), "v"(b));
  return c;
}
static __device__ __forceinline__ v2f pkfma_sb1(v2f a, v2f b, v2f c) {
  asm("v_pk_fma_f32 %0, %1, %2, %0 op_sel:[0,1,0] op_sel_hi:[1,1,1]"
      : "+v"(c) : "s"(a), "v"(b));
  return c;
}

// ws layout (floats): [0..575] A(24x24) | [576..2111] Wc(768x2) | [2112..2113] bc(2)
//                     | [2176..2751] AT(24x24)   (assumes ws_size >= 11008 B)

__global__ void prep_kernel(const int* __restrict__ ei, int ec,
                            const float* __restrict__ fcw1, const float* __restrict__ fcb1,
                            const float* __restrict__ fcw2, const float* __restrict__ fcb2,
                            float* __restrict__ ws) {
  int t = threadIdx.x;
  if (blockIdx.x == 0) {
    __shared__ float deg[NN];
    __shared__ float dinv[NN];
    __shared__ float As[NN*NN];
    __shared__ int s_is64;
    if (t == 0) s_is64 = 1;
    if (t < NN) deg[t] = 1.0f;            // self-loop contribution
    for (int k = t; k < NN*NN; k += T) As[k] = 0.0f;
    __syncthreads();
    // dtype sniff: int64 edge_index viewed as int32 has all odd (high) words == 0
    for (int k = t; k < 2*ec; k += T) {
      if (ei[2*k + 1] != 0) atomicExch(&s_is64, 0);
    }
    __syncthreads();
    int is64 = s_is64;
    for (int k = t; k < ec; k += T) {
      int d = is64 ? ei[2*(ec + k)] : ei[ec + k];
      atomicAdd(&deg[d], 1.0f);
    }
    __syncthreads();
    if (t < NN) dinv[t] = 1.0f / sqrtf(deg[t]);
    __syncthreads();
    for (int k = t; k < ec; k += T) {
      int s = is64 ? ei[2*k]        : ei[k];
      int d = is64 ? ei[2*(ec + k)] : ei[ec + k];
      atomicAdd(&As[d*NN + s], dinv[s]*dinv[d]);
    }
    if (t < NN) atomicAdd(&As[t*NN + t], dinv[t]*dinv[t]);  // self loop
    __syncthreads();
    for (int k = t; k < NN*NN; k += T) {
      float a = As[k];
      int r = k / NN, c = k % NN;
      ws[k] = a;                       // A (row-major), used by g1 stage
      ws[AT_OFF + c*NN + r] = a;       // A^T, used by column-form A-mix
    }
    if (t < 2) {
      float acc = fcb2[t];
      for (int k = 0; k < 128; ++k) acc += fcb1[k]*fcw2[k*2 + t];
      ws[2112 + t] = acc;
    }
  } else {
    // Wc = fcw1 @ fcw2 : blocks 1..8 compute 96 rows each (fcw2 transposed in LDS)
    __shared__ __align__(16) float w2t[256];
    for (int k = t; k < 256; k += T) w2t[(k & 1)*128 + (k >> 1)] = fcw2[k];
    __syncthreads();
    int r0 = (blockIdx.x - 1) * 96;
    for (int idx = t; idx < 96*2; idx += T) {
      int r = r0 + (idx >> 1), c = idx & 1;
      const v4f* w1r = (const v4f*)(fcw1 + r*128);
      const v4f* w2v = (const v4f*)(w2t + c*128);
      v4f s = (v4f){0.f, 0.f, 0.f, 0.f};
      #pragma unroll
      for (int k = 0; k < 32; ++k) s = w1r[k]*w2v[k] + s;
      ws[576 + r*2 + c] = (s.x + s.y) + (s.z + s.w);
    }
  }
}

// Merged step for L1-L4 (FOUT<=8): W-mix h col f in 12 v2f (pk-fma), barrier,
// column-form A-mix with ALL A operands via scalar pipe (s_load → "s" src0).
template<int FIN, int FOUT, int SPLIT>
__device__ __forceinline__ void merged_layer(const float* __restrict__ ATg, float* gbuf,
                                             const float* Ws, const float* bs, int t) {
  constexpr int NCOLS = EPB*FOUT;       // 64/64/128/128
  constexpr int CL    = NN/SPLIT;       // 6/6/12/12
  constexpr int NV    = CL/2;
  int col = t & (NCOLS - 1);
  int i0  = __builtin_amdgcn_readfirstlane((t / NCOLS) * CL);  // wave-uniform
  int e = col / FOUT;
  int f = col & (FOUT - 1);
  const float* ib = gbuf + e*ESTR;
  float wcol[FIN];
  #pragma unroll
  for (int fi = 0; fi < FIN; ++fi) wcol[fi] = Ws[fi*FOUT + f];
  float bf = bs[f];
  v2f hh[12];
  #pragma unroll
  for (int k = 0; k < 12; ++k) hh[k] = (v2f){bf, bf};
  #pragma unroll
  for (int fi = 0; fi < FIN; ++fi) {
    v2f w2 = (v2f){wcol[fi], wcol[fi]};
    const v4f* c4 = (const v4f*)(ib + fi*CSTR);
    #pragma unroll
    for (int k = 0; k < 6; ++k) {
      v4f v = c4[k];
      v2f lo = __builtin_shufflevector(v, v, 0, 1);
      v2f hi = __builtin_shufflevector(v, v, 2, 3);
      hh[2*k]   = pkfma(lo, w2, hh[2*k]);
      hh[2*k+1] = pkfma(hi, w2, hh[2*k+1]);
    }
  }
  #pragma unroll
  for (int k = 0; k < 12; ++k)
    hh[k] = __builtin_elementwise_max(hh[k], (v2f){0.f, 0.f});
  __syncthreads();           // all gbuf reads complete before in-place overwrite
  float* ob = gbuf + e*ESTR + f*CSTR + i0;
  v2f acc[NV] = {};
  #pragma unroll
  for (int jp = 0; jp < 12; ++jp) {
    v2f hp = hh[jp];
    const v2f* gA = (const v2f*)(ATg + (2*jp)*NN + i0);      // uniform → s_load
    const v2f* gB = (const v2f*)(ATg + (2*jp + 1)*NN + i0);
    #pragma unroll
    for (int k = 0; k < NV; ++k) {
      acc[k] = pkfma_sb0(gA[k], hp, acc[k]);
      acc[k] = pkfma_sb1(gB[k], hp, acc[k]);
    }
  }
  #pragma unroll
  for (int k = 0; k < NV; ++k) *(v2f*)(ob + 2*k) = acc[k];
}

// Fused 2-column layer for L5/L6 (FOUT=16): 128 tasks (e = t>>3, f0 = t&7,
// f1 = f0+8) on waves 0-1; each lane reads its elem's g ONCE and produces two
// h columns → halves the block's DS-pipe instruction demand for these layers.
// A-mix per column sequential (register-pressure-safe), SMEM operands shared.
template<int FIN>
__device__ __forceinline__ void fused16(const float* __restrict__ ATg, float* gbuf,
                                        const float* Ws, const float* bs, int t) {
  bool act = t < 128;
  int e = (t >> 3) & 15, f0 = t & 7;
  const float* ib = gbuf + e*ESTR;
  v2f hA[12], hB[12];
  if (act) {
    float bA = bs[f0], bB = bs[f0 + 8];
    #pragma unroll
    for (int k = 0; k < 12; ++k) { hA[k] = (v2f){bA, bA}; hB[k] = (v2f){bB, bB}; }
    #pragma unroll
    for (int fi = 0; fi < FIN; ++fi) {
      float wa = Ws[fi*16 + f0];
      float wb = Ws[fi*16 + f0 + 8];
      v2f wA2 = (v2f){wa, wa};
      v2f wB2 = (v2f){wb, wb};
      const v4f* c4 = (const v4f*)(ib + fi*CSTR);
      #pragma unroll
      for (int k = 0; k < 6; ++k) {
        v4f v = c4[k];
        v2f lo = __builtin_shufflevector(v, v, 0, 1);
        v2f hi = __builtin_shufflevector(v, v, 2, 3);
        hA[2*k]   = pkfma(lo, wA2, hA[2*k]);
        hA[2*k+1] = pkfma(hi, wA2, hA[2*k+1]);
        hB[2*k]   = pkfma(lo, wB2, hB[2*k]);
        hB[2*k+1] = pkfma(hi, wB2, hB[2*k+1]);
      }
    }
    #pragma unroll
    for (int k = 0; k < 12; ++k) {
      hA[k] = __builtin_elementwise_max(hA[k], (v2f){0.f, 0.f});
      hB[k] = __builtin_elementwise_max(hB[k], (v2f){0.f, 0.f});
    }
  }
  __syncthreads();           // all gbuf reads complete before in-place overwrite
  if (act) {
    float* ob0 = gbuf + e*ESTR + f0*CSTR;
    {
      v2f acc[12] = {};
      #pragma unroll
      for (int jp = 0; jp < 12; ++jp) {
        v2f hp = hA[jp];
        const v2f* gA = (const v2f*)(ATg + (2*jp)*NN);
        const v2f* gB = (const v2f*)(ATg + (2*jp + 1)*NN);
        #pragma unroll
        for (int k = 0; k < 12; ++k) {
          acc[k] = pkfma_sb0(gA[k], hp, acc[k]);
          acc[k] = pkfma_sb1(gB[k], hp, acc[k]);
        }
      }
      #pragma unroll
      for (int k = 0; k < 12; ++k) *(v2f*)(ob0 + 2*k) = acc[k];
    }
    {
      float* ob1 = ob0 + 8*CSTR;
      v2f acc[12] = {};
      #pragma unroll
      for (int jp = 0; jp < 12; ++jp) {
        v2f hp = hB[jp];
        const v2f* gA = (const v2f*)(ATg + (2*jp)*NN);
        const v2f* gB = (const v2f*)(ATg + (2*jp + 1)*NN);
        #pragma unroll
        for (int k = 0; k < 12; ++k) {
          acc[k] = pkfma_sb0(gA[k], hp, acc[k]);
          acc[k] = pkfma_sb1(gB[k], hp, acc[k]);
        }
      }
      #pragma unroll
      for (int k = 0; k < 12; ++k) *(v2f*)(ob1 + 2*k) = acc[k];
    }
  }
}

__global__ __launch_bounds__(256, 4) void gcn_main(
    const float* __restrict__ x, const float* __restrict__ ws,
    const float* __restrict__ W1, const float* __restrict__ b1,
    const float* __restrict__ W2, const float* __restrict__ b2,
    const float* __restrict__ W3, const float* __restrict__ b3,
    const float* __restrict__ W4, const float* __restrict__ b4,
    const float* __restrict__ W5, const float* __restrict__ b5,
    const float* __restrict__ W6, const float* __restrict__ b6,
    const float* __restrict__ W7, const float* __restrict__ b7,
    float* __restrict__ out) {
  __shared__ __align__(16) float gbuf[EPB*ESTR];  // 28928 B, single in-place buffer
  __shared__ float Wsh[500];                      // W1..W6; W7 read from global/L1
  __shared__ __align__(16) float bsh[88];
  int t = threadIdx.x;
  const float* ATg = ws + AT_OFF;       // wave-uniform: scalar-pipe delivery

  // stage layer weights/biases into LDS
  {
    const float* Wp[6] = {W1,W2,W3,W4,W5,W6};
    const float* bp[7] = {b1,b2,b3,b4,b5,b6,b7};
    const int wsz[6] = {4,16,32,64,128,256};
    const int wof[6] = {0,4,20,52,116,244};
    const int bsz[7] = {4,4,8,8,16,16,32};
    const int bof[7] = {0,4,8,16,24,40,56};
    #pragma unroll
    for (int l = 0; l < 6; ++l) {
      for (int k = t; k < wsz[l]; k += T) Wsh[wof[l] + k] = Wp[l][k];
    }
    #pragma unroll
    for (int l = 0; l < 7; ++l) {
      if (t < bsz[l]) bsh[bof[l] + t] = bp[l][t];
    }
  }
  // stage x tile into column slot 1 of each elem (col 0 gets g1 = A@x)
  {
    const float* xg = x + (size_t)blockIdx.x * (EPB*NN);
    if (t < EPB*NN/4) {
      float4 v = ((const float4*)xg)[t];
      int e = t/6, k = t - e*6;
      ((float4*)(gbuf + e*ESTR + CSTR))[k] = v;
    }
  }
  __syncthreads();

  // g1 = A @ x : 384 tasks (e, i); A rows per-lane from global (2.3 KB, L1-hot)
  {
    int e = t & 15, i = t >> 4;          // i in 0..15
    const float4* xv = (const float4*)(gbuf + e*ESTR + CSTR);
    const float4* Ar = (const float4*)(ws + i*NN);
    float acc = 0.f;
    #pragma unroll
    for (int k = 0; k < 6; ++k) {
      float4 a = Ar[k]; float4 v = xv[k];
      acc += a.x*v.x + a.y*v.y + a.z*v.z + a.w*v.w;
    }
    gbuf[e*ESTR + i] = acc;
    if (t < 128) {
      int i2 = 16 + (t >> 4);            // i in 16..23
      const float4* Ar2 = (const float4*)(ws + i2*NN);
      float acc2 = 0.f;
      #pragma unroll
      for (int k = 0; k < 6; ++k) {
        float4 a = Ar2[k]; float4 v = xv[k];
        acc2 += a.x*v.x + a.y*v.y + a.z*v.z + a.w*v.w;
      }
      gbuf[e*ESTR + i2] = acc2;
    }
  }
  __syncthreads();

  merged_layer<1, 4, 4>(ATg, gbuf, Wsh+0,   bsh+0,  t); __syncthreads();
  merged_layer<4, 4, 4>(ATg, gbuf, Wsh+4,   bsh+4,  t); __syncthreads();
  merged_layer<4, 8, 2>(ATg, gbuf, Wsh+20,  bsh+8,  t); __syncthreads();
  merged_layer<8, 8, 2>(ATg, gbuf, Wsh+52,  bsh+16, t); __syncthreads();
  fused16<8> (ATg, gbuf, Wsh+116, bsh+24, t);           __syncthreads();
  fused16<16>(ATg, gbuf, Wsh+244, bsh+40, t);           __syncthreads();

  // L7 + composed FC + log_softmax, 2-col fused: thread (e = t>>4, f0 = t&15,
  // f1 = f0+16) reads g ONCE for both columns; partial p's combined in-register,
  // reduction over 16 lanes.
  {
    const float* Wc = ws + 576;
    float bc0 = ws[2112], bc1 = ws[2113];
    int e = t >> 4, f0 = t & 15;
    const float* ib = gbuf + e*ESTR;
    float bA = bsh[56 + f0], bB = bsh[56 + f0 + 16];
    v2f hA[12], hB[12];
    #pragma unroll
    for (int k = 0; k < 12; ++k) { hA[k] = (v2f){bA, bA}; hB[k] = (v2f){bB, bB}; }
    #pragma unroll
    for (int fi = 0; fi < 16; ++fi) {
      float wa = W7[fi*32 + f0];       // global, L1-cached, coalesced
      float wb = W7[fi*32 + f0 + 16];
      v2f wA2 = (v2f){wa, wa};
      v2f wB2 = (v2f){wb, wb};
      const v4f* c4 = (const v4f*)(ib + fi*CSTR);
      #pragma unroll
      for (int k = 0; k < 6; ++k) {
        v4f v = c4[k];
        v2f lo = __builtin_shufflevector(v, v, 0, 1);
        v2f hi = __builtin_shufflevector(v, v, 2, 3);
        hA[2*k]   = pkfma(lo, wA2, hA[2*k]);
        hA[2*k+1] = pkfma(hi, wA2, hA[2*k+1]);
        hB[2*k]   = pkfma(lo, wB2, hB[2*k]);
        hB[2*k+1] = pkfma(hi, wB2, hB[2*k+1]);
      }
    }
    #pragma unroll
    for (int k = 0; k < 12; ++k) {
      hA[k] = __builtin_elementwise_max(hA[k], (v2f){0.f, 0.f});
      hB[k] = __builtin_elementwise_max(hB[k], (v2f){0.f, 0.f});
    }
    v2f p = (v2f){0.f, 0.f};           // (p0, p1)
    #pragma unroll
    for (int kp = 0; kp < 12; ++kp) {
      v2f hpA = hA[kp], hpB = hB[kp];
      v2f wcA0 = *(const v2f*)(Wc + ((2*kp)*32 + f0)*2);
      v2f wcA1 = *(const v2f*)(Wc + ((2*kp + 1)*32 + f0)*2);
      v2f wcB0 = *(const v2f*)(Wc + ((2*kp)*32 + f0 + 16)*2);
      v2f wcB1 = *(const v2f*)(Wc + ((2*kp + 1)*32 + f0 + 16)*2);
      p = pkfma_b0(wcA0, hpA, p);
      p = pkfma_b1(wcA1, hpA, p);
      p = pkfma_b0(wcB0, hpB, p);
      p = pkfma_b1(wcB1, hpB, p);
    }
    float p0 = p.x, p1 = p.y;
    #pragma unroll
    for (int m = 1; m < 16; m <<= 1) {
      p0 += __shfl_xor(p0, m, 16);
      p1 += __shfl_xor(p1, m, 16);
    }
    if (f0 < 2) {
      float z0 = p0 + bc0, z1 = p1 + bc1;
      float mx = fmaxf(z0, z1);
      float lse = mx + logf(expf(z0 - mx) + expf(z1 - mx));
      int eg = blockIdx.x*EPB + e;
      out[eg*2 + f0] = (f0 == 0 ? z0 : z1) - lse;
    }
  }
}

extern "C" void kernel_launch(void* const* d_in, const int* in_sizes, int n_in,
                              void* d_out, int out_size, void* d_ws, size_t ws_size,
                              hipStream_t stream) {
  const float* x    = (const float*)d_in[0];
  const int*   ei   = (const int*)  d_in[1];
  const float* W1   = (const float*)d_in[2];  const float* b1 = (const float*)d_in[3];
  const float* W2   = (const float*)d_in[4];  const float* b2 = (const float*)d_in[5];
  const float* W3   = (const float*)d_in[6];  const float* b3 = (const float*)d_in[7];
  const float* W4   = (const float*)d_in[8];  const float* b4 = (const float*)d_in[9];
  const float* W5   = (const float*)d_in[10]; const float* b5 = (const float*)d_in[11];
  const float* W6   = (const float*)d_in[12]; const float* b6 = (const float*)d_in[13];
  const float* W7   = (const float*)d_in[14]; const float* b7 = (const float*)d_in[15];
  const float* fcw1 = (const float*)d_in[16]; const float* fcb1 = (const float*)d_in[17];
  const float* fcw2 = (const float*)d_in[18]; const float* fcb2 = (const float*)d_in[19];
  float* out = (float*)d_out;
  float* ws  = (float*)d_ws;
  int ec = in_sizes[1] / 2;        // 96 edges
  int B  = in_sizes[0] / NN;       // 32768

  hipLaunchKernelGGL(prep_kernel, dim3(9), dim3(T), 0, stream,
                     ei, ec, fcw1, fcb1, fcw2, fcb2, ws);
  hipLaunchKernelGGL(gcn_main, dim3(B/EPB), dim3(T), 0, stream,
                     x, ws, W1,b1, W2,b2, W3,b3, W4,b4, W5,b5, W6,b6, W7,b7, out);
}

// Round 9
// 218.658 us; speedup vs baseline: 1.0093x; 1.0093x over previous
//
#include <hip/hip_runtime.h>
#include <math.h>

#define NN   24          // nodes per graph
#define EPB  16          // graph elements per block
#define CSTR 28          // LDS column stride (floats): 24 + 4 pad, 16B aligned
#define ESTR 452         // per-elem stride: 16*28 + 4 → e-stride ≡ 4 banks mod 32
#define T    256
#define AT_OFF 2176      // A^T (24x24) in ws, 16B-aligned float offset

typedef float v2f __attribute__((ext_vector_type(2)));
typedef float v4f __attribute__((ext_vector_type(4)));

// Guaranteed packed math: d = a*b + c on 2xf32 register pairs.
static __device__ __forceinline__ v2f pkfma(v2f a, v2f b, v2f c) {
  asm("v_pk_fma_f32 %0, %1, %2, %0" : "+v"(c) : "v"(a), "v"(b));
  return c;
}
// c += a * broadcast(b.lo)  (src1 low half replicated via op_sel — no splat mov)
static __device__ __forceinline__ v2f pkfma_b0(v2f a, v2f b, v2f c) {
  asm("v_pk_fma_f32 %0, %1, %2, %0 op_sel:[0,0,0] op_sel_hi:[1,0,1]"
      : "+v"(c) : "v"(a), "v"(b));
  return c;
}
// c += a * broadcast(b.hi)
static __device__ __forceinline__ v2f pkfma_b1(v2f a, v2f b, v2f c) {
  asm("v_pk_fma_f32 %0, %1, %2, %0 op_sel:[0,1,0] op_sel_hi:[1,1,1]"
      : "+v"(c) : "v"(a), "v"(b));
  return c;
}
// Same, but a (src0) delivered from an SGPR pair — scalar-pipe operand flow.
// VOP3P allows one SGPR operand; avoids both LDS traffic and s->v movs.
static __device__ __forceinline__ v2f pkfma_sb0(v2f a, v2f b, v2f c) {
  asm("v_pk_fma_f32 %0, %1, %2, %0 op_sel:[0,0,0] op_sel_hi:[1,0,1]"
      : "+v"(c) : "s"(a), "v"(b));
  return c;
}
static __device__ __forceinline__ v2f pkfma_sb1(v2f a, v2f b, v2f c) {
  asm("v_pk_fma_f32 %0, %1, %2, %0 op_sel:[0,1,0] op_sel_hi:[1,1,1]"
      : "+v"(c) : "s"(a), "v"(b));
  return c;
}

// ws layout (floats): [0..575] A(24x24) | [576..2111] Wc(768x2) | [2112..2113] bc(2)
//                     | [2176..2751] AT(24x24)   (assumes ws_size >= 11008 B)

__global__ void prep_kernel(const int* __restrict__ ei, int ec,
                            const float* __restrict__ fcw1, const float* __restrict__ fcb1,
                            const float* __restrict__ fcw2, const float* __restrict__ fcb2,
                            float* __restrict__ ws) {
  int t = threadIdx.x;
  if (blockIdx.x == 0) {
    __shared__ float deg[NN];
    __shared__ float dinv[NN];
    __shared__ float As[NN*NN];
    __shared__ int s_is64;
    if (t == 0) s_is64 = 1;
    if (t < NN) deg[t] = 1.0f;            // self-loop contribution
    for (int k = t; k < NN*NN; k += T) As[k] = 0.0f;
    __syncthreads();
    // dtype sniff: int64 edge_index viewed as int32 has all odd (high) words == 0
    for (int k = t; k < 2*ec; k += T) {
      if (ei[2*k + 1] != 0) atomicExch(&s_is64, 0);
    }
    __syncthreads();
    int is64 = s_is64;
    for (int k = t; k < ec; k += T) {
      int d = is64 ? ei[2*(ec + k)] : ei[ec + k];
      atomicAdd(&deg[d], 1.0f);
    }
    __syncthreads();
    if (t < NN) dinv[t] = 1.0f / sqrtf(deg[t]);
    __syncthreads();
    for (int k = t; k < ec; k += T) {
      int s = is64 ? ei[2*k]        : ei[k];
      int d = is64 ? ei[2*(ec + k)] : ei[ec + k];
      atomicAdd(&As[d*NN + s], dinv[s]*dinv[d]);
    }
    if (t < NN) atomicAdd(&As[t*NN + t], dinv[t]*dinv[t]);  // self loop
    __syncthreads();
    for (int k = t; k < NN*NN; k += T) {
      float a = As[k];
      int r = k / NN, c = k % NN;
      ws[k] = a;                       // A (row-major), used by g1 stage
      ws[AT_OFF + c*NN + r] = a;       // A^T, used by column-form A-mix
    }
    if (t < 2) {
      float acc = fcb2[t];
      for (int k = 0; k < 128; ++k) acc += fcb1[k]*fcw2[k*2 + t];
      ws[2112 + t] = acc;
    }
  } else {
    // Wc = fcw1 @ fcw2 : blocks 1..8 compute 96 rows each (fcw2 transposed in LDS)
    __shared__ __align__(16) float w2t[256];
    for (int k = t; k < 256; k += T) w2t[(k & 1)*128 + (k >> 1)] = fcw2[k];
    __syncthreads();
    int r0 = (blockIdx.x - 1) * 96;
    for (int idx = t; idx < 96*2; idx += T) {
      int r = r0 + (idx >> 1), c = idx & 1;
      const v4f* w1r = (const v4f*)(fcw1 + r*128);
      const v4f* w2v = (const v4f*)(w2t + c*128);
      v4f s = (v4f){0.f, 0.f, 0.f, 0.f};
      #pragma unroll
      for (int k = 0; k < 32; ++k) s = w1r[k]*w2v[k] + s;
      ws[576 + r*2 + c] = (s.x + s.y) + (s.z + s.w);
    }
  }
}

// Merged step for L1-L4 (FOUT<=8): W-mix h col f in 12 v2f (pk-fma), barrier,
// column-form A-mix with ALL A operands via scalar pipe (s_load → "s" src0).
template<int FIN, int FOUT, int SPLIT>
__device__ __forceinline__ void merged_layer(const float* __restrict__ ATg, float* gbuf,
                                             const float* Ws, const float* bs, int t) {
  constexpr int NCOLS = EPB*FOUT;       // 64/64/128/128
  constexpr int CL    = NN/SPLIT;       // 6/6/12/12
  constexpr int NV    = CL/2;
  int col = t & (NCOLS - 1);
  int i0  = __builtin_amdgcn_readfirstlane((t / NCOLS) * CL);  // wave-uniform
  int e = col / FOUT;
  int f = col & (FOUT - 1);
  const float* ib = gbuf + e*ESTR;
  float wcol[FIN];
  #pragma unroll
  for (int fi = 0; fi < FIN; ++fi) wcol[fi] = Ws[fi*FOUT + f];
  float bf = bs[f];
  v2f hh[12];
  #pragma unroll
  for (int k = 0; k < 12; ++k) hh[k] = (v2f){bf, bf};
  #pragma unroll
  for (int fi = 0; fi < FIN; ++fi) {
    v2f w2 = (v2f){wcol[fi], wcol[fi]};
    const v4f* c4 = (const v4f*)(ib + fi*CSTR);
    #pragma unroll
    for (int k = 0; k < 6; ++k) {
      v4f v = c4[k];
      v2f lo = __builtin_shufflevector(v, v, 0, 1);
      v2f hi = __builtin_shufflevector(v, v, 2, 3);
      hh[2*k]   = pkfma(lo, w2, hh[2*k]);
      hh[2*k+1] = pkfma(hi, w2, hh[2*k+1]);
    }
  }
  #pragma unroll
  for (int k = 0; k < 12; ++k)
    hh[k] = __builtin_elementwise_max(hh[k], (v2f){0.f, 0.f});
  __syncthreads();           // all gbuf reads complete before in-place overwrite
  float* ob = gbuf + e*ESTR + f*CSTR + i0;
  v2f acc[NV] = {};
  #pragma unroll
  for (int jp = 0; jp < 12; ++jp) {
    v2f hp = hh[jp];
    const v2f* gA = (const v2f*)(ATg + (2*jp)*NN + i0);      // uniform → s_load
    const v2f* gB = (const v2f*)(ATg + (2*jp + 1)*NN + i0);
    #pragma unroll
    for (int k = 0; k < NV; ++k) {
      acc[k] = pkfma_sb0(gA[k], hp, acc[k]);
      acc[k] = pkfma_sb1(gB[k], hp, acc[k]);
    }
  }
  #pragma unroll
  for (int k = 0; k < NV; ++k) *(v2f*)(ob + 2*k) = acc[k];
}

// Fused 2-column layer for L5/L6 (FOUT=16): 128 tasks (e = t>>3, f0 = t&7,
// f1 = f0+8) on waves 0-1; each lane reads its elem's g ONCE and produces two
// h columns → halves the block's DS-pipe instruction demand for these layers.
// A-mix per column sequential (hA dead before col-B acc), SMEM operands shared.
template<int FIN>
__device__ __forceinline__ void fused16(const float* __restrict__ ATg, float* gbuf,
                                        const float* Ws, const float* bs, int t) {
  bool act = t < 128;
  int e = (t >> 3) & 15, f0 = t & 7;
  const float* ib = gbuf + e*ESTR;
  v2f hA[12], hB[12];
  if (act) {
    float bA = bs[f0], bB = bs[f0 + 8];
    #pragma unroll
    for (int k = 0; k < 12; ++k) { hA[k] = (v2f){bA, bA}; hB[k] = (v2f){bB, bB}; }
    #pragma unroll
    for (int fi = 0; fi < FIN; ++fi) {
      float wa = Ws[fi*16 + f0];
      float wb = Ws[fi*16 + f0 + 8];
      v2f wA2 = (v2f){wa, wa};
      v2f wB2 = (v2f){wb, wb};
      const v4f* c4 = (const v4f*)(ib + fi*CSTR);
      #pragma unroll
      for (int k = 0; k < 6; ++k) {
        v4f v = c4[k];
        v2f lo = __builtin_shufflevector(v, v, 0, 1);
        v2f hi = __builtin_shufflevector(v, v, 2, 3);
        hA[2*k]   = pkfma(lo, wA2, hA[2*k]);
        hA[2*k+1] = pkfma(hi, wA2, hA[2*k+1]);
        hB[2*k]   = pkfma(lo, wB2, hB[2*k]);
        hB[2*k+1] = pkfma(hi, wB2, hB[2*k+1]);
      }
    }
    #pragma unroll
    for (int k = 0; k < 12; ++k) {
      hA[k] = __builtin_elementwise_max(hA[k], (v2f){0.f, 0.f});
      hB[k] = __builtin_elementwise_max(hB[k], (v2f){0.f, 0.f});
    }
  }
  __syncthreads();           // all gbuf reads complete before in-place overwrite
  if (act) {
    float* ob0 = gbuf + e*ESTR + f0*CSTR;
    {
      v2f acc[12] = {};
      #pragma unroll
      for (int jp = 0; jp < 12; ++jp) {
        v2f hp = hA[jp];
        const v2f* gA = (const v2f*)(ATg + (2*jp)*NN);
        const v2f* gB = (const v2f*)(ATg + (2*jp + 1)*NN);
        #pragma unroll
        for (int k = 0; k < 12; ++k) {
          acc[k] = pkfma_sb0(gA[k], hp, acc[k]);
          acc[k] = pkfma_sb1(gB[k], hp, acc[k]);
        }
      }
      #pragma unroll
      for (int k = 0; k < 12; ++k) *(v2f*)(ob0 + 2*k) = acc[k];
    }
    {
      float* ob1 = ob0 + 8*CSTR;
      v2f acc[12] = {};
      #pragma unroll
      for (int jp = 0; jp < 12; ++jp) {
        v2f hp = hB[jp];
        const v2f* gA = (const v2f*)(ATg + (2*jp)*NN);
        const v2f* gB = (const v2f*)(ATg + (2*jp + 1)*NN);
        #pragma unroll
        for (int k = 0; k < 12; ++k) {
          acc[k] = pkfma_sb0(gA[k], hp, acc[k]);
          acc[k] = pkfma_sb1(gB[k], hp, acc[k]);
        }
      }
      #pragma unroll
      for (int k = 0; k < 12; ++k) *(v2f*)(ob1 + 2*k) = acc[k];
    }
  }
}

// Pin the allocator: min=max=4 waves/EU → exactly 128 VGPRs available, removing
// the occupancy-chasing heuristic that spilled rounds 2/8 at 64 VGPRs.
__global__ __attribute__((amdgpu_flat_work_group_size(256, 256),
                          amdgpu_waves_per_eu(4, 4)))
void gcn_main(
    const float* __restrict__ x, const float* __restrict__ ws,
    const float* __restrict__ W1, const float* __restrict__ b1,
    const float* __restrict__ W2, const float* __restrict__ b2,
    const float* __restrict__ W3, const float* __restrict__ b3,
    const float* __restrict__ W4, const float* __restrict__ b4,
    const float* __restrict__ W5, const float* __restrict__ b5,
    const float* __restrict__ W6, const float* __restrict__ b6,
    const float* __restrict__ W7, const float* __restrict__ b7,
    float* __restrict__ out) {
  __shared__ __align__(16) float gbuf[EPB*ESTR];  // 28928 B, single in-place buffer
  __shared__ float Wsh[500];                      // W1..W6; W7 read from global/L1
  __shared__ __align__(16) float bsh[88];
  int t = threadIdx.x;
  const float* ATg = ws + AT_OFF;       // wave-uniform: scalar-pipe delivery

  // stage layer weights/biases into LDS
  {
    const float* Wp[6] = {W1,W2,W3,W4,W5,W6};
    const float* bp[7] = {b1,b2,b3,b4,b5,b6,b7};
    const int wsz[6] = {4,16,32,64,128,256};
    const int wof[6] = {0,4,20,52,116,244};
    const int bsz[7] = {4,4,8,8,16,16,32};
    const int bof[7] = {0,4,8,16,24,40,56};
    #pragma unroll
    for (int l = 0; l < 6; ++l) {
      for (int k = t; k < wsz[l]; k += T) Wsh[wof[l] + k] = Wp[l][k];
    }
    #pragma unroll
    for (int l = 0; l < 7; ++l) {
      if (t < bsz[l]) bsh[bof[l] + t] = bp[l][t];
    }
  }
  // stage x tile into column slot 1 of each elem (col 0 gets g1 = A@x)
  {
    const float* xg = x + (size_t)blockIdx.x * (EPB*NN);
    if (t < EPB*NN/4) {
      float4 v = ((const float4*)xg)[t];
      int e = t/6, k = t - e*6;
      ((float4*)(gbuf + e*ESTR + CSTR))[k] = v;
    }
  }
  __syncthreads();

  // g1 = A @ x : 384 tasks (e, i); A rows per-lane from global (2.3 KB, L1-hot)
  {
    int e = t & 15, i = t >> 4;          // i in 0..15
    const float4* xv = (const float4*)(gbuf + e*ESTR + CSTR);
    const float4* Ar = (const float4*)(ws + i*NN);
    float acc = 0.f;
    #pragma unroll
    for (int k = 0; k < 6; ++k) {
      float4 a = Ar[k]; float4 v = xv[k];
      acc += a.x*v.x + a.y*v.y + a.z*v.z + a.w*v.w;
    }
    gbuf[e*ESTR + i] = acc;
    if (t < 128) {
      int i2 = 16 + (t >> 4);            // i in 16..23
      const float4* Ar2 = (const float4*)(ws + i2*NN);
      float acc2 = 0.f;
      #pragma unroll
      for (int k = 0; k < 6; ++k) {
        float4 a = Ar2[k]; float4 v = xv[k];
        acc2 += a.x*v.x + a.y*v.y + a.z*v.z + a.w*v.w;
      }
      gbuf[e*ESTR + i2] = acc2;
    }
  }
  __syncthreads();

  merged_layer<1, 4, 4>(ATg, gbuf, Wsh+0,   bsh+0,  t); __syncthreads();
  merged_layer<4, 4, 4>(ATg, gbuf, Wsh+4,   bsh+4,  t); __syncthreads();
  merged_layer<4, 8, 2>(ATg, gbuf, Wsh+20,  bsh+8,  t); __syncthreads();
  merged_layer<8, 8, 2>(ATg, gbuf, Wsh+52,  bsh+16, t); __syncthreads();
  fused16<8> (ATg, gbuf, Wsh+116, bsh+24, t);           __syncthreads();
  fused16<16>(ATg, gbuf, Wsh+244, bsh+40, t);           __syncthreads();

  // L7 + composed FC + log_softmax, 2-col fused with ROW-HALF PASSES:
  // thread (e = t>>4, f0 = t&15, f1 = f0+16) reads each g row-half once,
  // computes hA/hB for those 12 rows (6 v2f each — low pressure), folds the
  // partial P-mix into p, and discards. p accumulates across passes; 16-lane
  // reduction at the end. g read once per elem (96 b128 vs round-6's 192).
  {
    const float* Wc = ws + 576;
    float bc0 = ws[2112], bc1 = ws[2113];
    int e = t >> 4, f0 = t & 15;
    const float* ib = gbuf + e*ESTR;
    float bA = bsh[56 + f0], bB = bsh[56 + f0 + 16];
    v2f p = (v2f){0.f, 0.f};           // (p0, p1)
    #pragma unroll
    for (int half = 0; half < 2; ++half) {
      v2f hA[6], hB[6];
      #pragma unroll
      for (int k = 0; k < 6; ++k) { hA[k] = (v2f){bA, bA}; hB[k] = (v2f){bB, bB}; }
      #pragma unroll
      for (int fi = 0; fi < 16; ++fi) {
        float wa = W7[fi*32 + f0];     // global, L1-cached, coalesced
        float wb = W7[fi*32 + f0 + 16];
        v2f wA2 = (v2f){wa, wa};
        v2f wB2 = (v2f){wb, wb};
        const v4f* c4 = (const v4f*)(ib + fi*CSTR + half*12);
        #pragma unroll
        for (int k = 0; k < 3; ++k) {
          v4f v = c4[k];
          v2f lo = __builtin_shufflevector(v, v, 0, 1);
          v2f hi = __builtin_shufflevector(v, v, 2, 3);
          hA[2*k]   = pkfma(lo, wA2, hA[2*k]);
          hA[2*k+1] = pkfma(hi, wA2, hA[2*k+1]);
          hB[2*k]   = pkfma(lo, wB2, hB[2*k]);
          hB[2*k+1] = pkfma(hi, wB2, hB[2*k+1]);
        }
      }
      #pragma unroll
      for (int k = 0; k < 6; ++k) {
        hA[k] = __builtin_elementwise_max(hA[k], (v2f){0.f, 0.f});
        hB[k] = __builtin_elementwise_max(hB[k], (v2f){0.f, 0.f});
      }
      #pragma unroll
      for (int m = 0; m < 6; ++m) {
        int kg = half*6 + m;           // global row pair: rows 2kg, 2kg+1
        v2f hpA = hA[m], hpB = hB[m];
        v2f wcA0 = *(const v2f*)(Wc + ((2*kg)*32 + f0)*2);
        v2f wcA1 = *(const v2f*)(Wc + ((2*kg + 1)*32 + f0)*2);
        v2f wcB0 = *(const v2f*)(Wc + ((2*kg)*32 + f0 + 16)*2);
        v2f wcB1 = *(const v2f*)(Wc + ((2*kg + 1)*32 + f0 + 16)*2);
        p = pkfma_b0(wcA0, hpA, p);
        p = pkfma_b1(wcA1, hpA, p);
        p = pkfma_b0(wcB0, hpB, p);
        p = pkfma_b1(wcB1, hpB, p);
      }
    }
    float p0 = p.x, p1 = p.y;
    #pragma unroll
    for (int m = 1; m < 16; m <<= 1) {
      p0 += __shfl_xor(p0, m, 16);
      p1 += __shfl_xor(p1, m, 16);
    }
    if (f0 < 2) {
      float z0 = p0 + bc0, z1 = p1 + bc1;
      float mx = fmaxf(z0, z1);
      float lse = mx + logf(expf(z0 - mx) + expf(z1 - mx));
      int eg = blockIdx.x*EPB + e;
      out[eg*2 + f0] = (f0 == 0 ? z0 : z1) - lse;
    }
  }
}

extern "C" void kernel_launch(void* const* d_in, const int* in_sizes, int n_in,
                              void* d_out, int out_size, void* d_ws, size_t ws_size,
                              hipStream_t stream) {
  const float* x    = (const float*)d_in[0];
  const int*   ei   = (const int*)  d_in[1];
  const float* W1   = (const float*)d_in[2];  const float* b1 = (const float*)d_in[3];
  const float* W2   = (const float*)d_in[4];  const float* b2 = (const float*)d_in[5];
  const float* W3   = (const float*)d_in[6];  const float* b3 = (const float*)d_in[7];
  const float* W4   = (const float*)d_in[8];  const float* b4 = (const float*)d_in[9];
  const float* W5   = (const float*)d_in[10]; const float* b5 = (const float*)d_in[11];
  const float* W6   = (const float*)d_in[12]; const float* b6 = (const float*)d_in[13];
  const float* W7   = (const float*)d_in[14]; const float* b7 = (const float*)d_in[15];
  const float* fcw1 = (const float*)d_in[16]; const float* fcb1 = (const float*)d_in[17];
  const float* fcw2 = (const float*)d_in[18]; const float* fcb2 = (const float*)d_in[19];
  float* out = (float*)d_out;
  float* ws  = (float*)d_ws;
  int ec = in_sizes[1] / 2;        // 96 edges
  int B  = in_sizes[0] / NN;       // 32768

  hipLaunchKernelGGL(prep_kernel, dim3(9), dim3(T), 0, stream,
                     ei, ec, fcw1, fcb1, fcw2, fcb2, ws);
  hipLaunchKernelGGL(gcn_main, dim3(B/EPB), dim3(T), 0, stream,
                     x, ws, W1,b1, W2,b2, W3,b3, W4,b4, W5,b5, W6,b6, W7,b7, out);
}

// Round 10
// 155.068 us; speedup vs baseline: 1.4232x; 1.4101x over previous
//
#include <hip/hip_runtime.h>
#include <math.h>

#define NN   24          // nodes per graph
#define EPB  16          // graph elements per block
#define CSTR 28          // LDS column stride (floats): 24 + 4 pad, 16B aligned
#define ESTR 452         // per-elem stride: 16*28 + 4 → e-stride ≡ 4 banks mod 32
#define T    256
#define AT_OFF 2176      // A^T (24x24) in ws, 16B-aligned float offset

typedef float v2f __attribute__((ext_vector_type(2)));
typedef float v4f __attribute__((ext_vector_type(4)));

// Guaranteed packed math: d = a*b + c on 2xf32 register pairs.
static __device__ __forceinline__ v2f pkfma(v2f a, v2f b, v2f c) {
  asm("v_pk_fma_f32 %0, %1, %2, %0" : "+v"(c) : "v"(a), "v"(b));
  return c;
}
// c += a * broadcast(b.lo)  (src1 low half replicated via op_sel — no splat mov)
static __device__ __forceinline__ v2f pkfma_b0(v2f a, v2f b, v2f c) {
  asm("v_pk_fma_f32 %0, %1, %2, %0 op_sel:[0,0,0] op_sel_hi:[1,0,1]"
      : "+v"(c) : "v"(a), "v"(b));
  return c;
}
// c += a * broadcast(b.hi)
static __device__ __forceinline__ v2f pkfma_b1(v2f a, v2f b, v2f c) {
  asm("v_pk_fma_f32 %0, %1, %2, %0 op_sel:[0,1,0] op_sel_hi:[1,1,1]"
      : "+v"(c) : "v"(a), "v"(b));
  return c;
}
// Same, but a (src0) delivered from an SGPR pair — scalar-pipe operand flow.
// VOP3P allows one SGPR operand; avoids both LDS traffic and s->v movs.
static __device__ __forceinline__ v2f pkfma_sb0(v2f a, v2f b, v2f c) {
  asm("v_pk_fma_f32 %0, %1, %2, %0 op_sel:[0,0,0] op_sel_hi:[1,0,1]"
      : "+v"(c) : "s"(a), "v"(b));
  return c;
}
static __device__ __forceinline__ v2f pkfma_sb1(v2f a, v2f b, v2f c) {
  asm("v_pk_fma_f32 %0, %1, %2, %0 op_sel:[0,1,0] op_sel_hi:[1,1,1]"
      : "+v"(c) : "s"(a), "v"(b));
  return c;
}

// ws layout (floats): [0..575] A(24x24) | [576..2111] Wc(768x2) | [2112..2113] bc(2)
//                     | [2176..2751] AT(24x24)   (assumes ws_size >= 11008 B)

__global__ void prep_kernel(const int* __restrict__ ei, int ec,
                            const float* __restrict__ fcw1, const float* __restrict__ fcb1,
                            const float* __restrict__ fcw2, const float* __restrict__ fcb2,
                            float* __restrict__ ws) {
  int t = threadIdx.x;
  if (blockIdx.x == 0) {
    __shared__ float deg[NN];
    __shared__ float dinv[NN];
    __shared__ float As[NN*NN];
    __shared__ int s_is64;
    if (t == 0) s_is64 = 1;
    if (t < NN) deg[t] = 1.0f;            // self-loop contribution
    for (int k = t; k < NN*NN; k += T) As[k] = 0.0f;
    __syncthreads();
    // dtype sniff: int64 edge_index viewed as int32 has all odd (high) words == 0
    for (int k = t; k < 2*ec; k += T) {
      if (ei[2*k + 1] != 0) atomicExch(&s_is64, 0);
    }
    __syncthreads();
    int is64 = s_is64;
    for (int k = t; k < ec; k += T) {
      int d = is64 ? ei[2*(ec + k)] : ei[ec + k];
      atomicAdd(&deg[d], 1.0f);
    }
    __syncthreads();
    if (t < NN) dinv[t] = 1.0f / sqrtf(deg[t]);
    __syncthreads();
    for (int k = t; k < ec; k += T) {
      int s = is64 ? ei[2*k]        : ei[k];
      int d = is64 ? ei[2*(ec + k)] : ei[ec + k];
      atomicAdd(&As[d*NN + s], dinv[s]*dinv[d]);
    }
    if (t < NN) atomicAdd(&As[t*NN + t], dinv[t]*dinv[t]);  // self loop
    __syncthreads();
    for (int k = t; k < NN*NN; k += T) {
      float a = As[k];
      int r = k / NN, c = k % NN;
      ws[k] = a;                       // A (row-major), used by g1 stage
      ws[AT_OFF + c*NN + r] = a;       // A^T, used by column-form A-mix
    }
    if (t < 2) {
      float acc = fcb2[t];
      for (int k = 0; k < 128; ++k) acc += fcb1[k]*fcw2[k*2 + t];
      ws[2112 + t] = acc;
    }
  } else {
    // Wc = fcw1 @ fcw2 : blocks 1..8 compute 96 rows each (fcw2 transposed in LDS)
    __shared__ __align__(16) float w2t[256];
    for (int k = t; k < 256; k += T) w2t[(k & 1)*128 + (k >> 1)] = fcw2[k];
    __syncthreads();
    int r0 = (blockIdx.x - 1) * 96;
    for (int idx = t; idx < 96*2; idx += T) {
      int r = r0 + (idx >> 1), c = idx & 1;
      const v4f* w1r = (const v4f*)(fcw1 + r*128);
      const v4f* w2v = (const v4f*)(w2t + c*128);
      v4f s = (v4f){0.f, 0.f, 0.f, 0.f};
      #pragma unroll
      for (int k = 0; k < 32; ++k) s = w1r[k]*w2v[k] + s;
      ws[576 + r*2 + c] = (s.x + s.y) + (s.z + s.w);
    }
  }
}

// Merged step: gbuf holds g_l = A @ h_{l-1} (FIN cols per elem).
// W-mix: h col f = relu(g_l @ W + b) held as 12 v2f pairs (asm v_pk_fma_f32).
// BARRIER, then COLUMN-form A-mix: out[i] = sum_j AT[j][i]*h[j], accumulated in
// aligned v2f pairs. AT pairs arrive via the SCALAR pipe (s_load → SGPR-pair
// src0); h[j] broadcast comes free via op_sel. Zero vector-pipe A traffic.
template<int FIN, int FOUT, int SPLIT>
__device__ __forceinline__ void merged_layer(const float* __restrict__ ATg, float* gbuf,
                                             const float* Ws, const float* bs, int t) {
  constexpr int NCOLS = EPB*FOUT;       // 64/64/128/128/256/256
  constexpr int CL    = NN/SPLIT;       // 6/6/12/12/24/24
  constexpr int NV    = CL/2;
  int col = t & (NCOLS - 1);
  int i0  = __builtin_amdgcn_readfirstlane((t / NCOLS) * CL);  // wave-uniform
  int e = col / FOUT;
  int f = col & (FOUT - 1);
  const float* ib = gbuf + e*ESTR;
  // hoist W column + bias (batched LDS b32 reads, latency overlapped)
  float wcol[FIN];
  #pragma unroll
  for (int fi = 0; fi < FIN; ++fi) wcol[fi] = Ws[fi*FOUT + f];
  float bf = bs[f];
  v2f hh[12];
  #pragma unroll
  for (int k = 0; k < 12; ++k) hh[k] = (v2f){bf, bf};
  #pragma unroll
  for (int fi = 0; fi < FIN; ++fi) {
    v2f w2 = (v2f){wcol[fi], wcol[fi]};
    const v4f* c4 = (const v4f*)(ib + fi*CSTR);
    #pragma unroll
    for (int k = 0; k < 6; ++k) {
      v4f v = c4[k];
      v2f lo = __builtin_shufflevector(v, v, 0, 1);
      v2f hi = __builtin_shufflevector(v, v, 2, 3);
      hh[2*k]   = pkfma(lo, w2, hh[2*k]);
      hh[2*k+1] = pkfma(hi, w2, hh[2*k+1]);
    }
  }
  #pragma unroll
  for (int k = 0; k < 12; ++k)
    hh[k] = __builtin_elementwise_max(hh[k], (v2f){0.f, 0.f});
  __syncthreads();           // all gbuf reads complete before in-place overwrite
  // A-mix, column form over rows i0..i0+CL-1; jp runs over h pairs (elems 0/1)
  float* ob = gbuf + e*ESTR + f*CSTR + i0;
  v2f acc[NV] = {};
  #pragma unroll
  for (int jp = 0; jp < 12; ++jp) {
    v2f hp = hh[jp];
    const v2f* gA = (const v2f*)(ATg + (2*jp)*NN + i0);      // uniform → s_load
    const v2f* gB = (const v2f*)(ATg + (2*jp + 1)*NN + i0);
    #pragma unroll
    for (int k = 0; k < NV; ++k) {
      acc[k] = pkfma_sb0(gA[k], hp, acc[k]);
      acc[k] = pkfma_sb1(gB[k], hp, acc[k]);
    }
  }
  #pragma unroll
  for (int k = 0; k < NV; ++k) *(v2f*)(ob + 2*k) = acc[k];
}

__global__ __launch_bounds__(256, 4) void gcn_main(
    const float* __restrict__ x, const float* __restrict__ ws,
    const float* __restrict__ W1, const float* __restrict__ b1,
    const float* __restrict__ W2, const float* __restrict__ b2,
    const float* __restrict__ W3, const float* __restrict__ b3,
    const float* __restrict__ W4, const float* __restrict__ b4,
    const float* __restrict__ W5, const float* __restrict__ b5,
    const float* __restrict__ W6, const float* __restrict__ b6,
    const float* __restrict__ W7, const float* __restrict__ b7,
    float* __restrict__ out) {
  __shared__ __align__(16) float gbuf[EPB*ESTR];  // 28928 B, single in-place buffer
  __shared__ float Wsh[500];                      // W1..W6; W7 read from global/L1
  __shared__ __align__(16) float bsh[88];
  int t = threadIdx.x;
  const float* ATg = ws + AT_OFF;       // wave-uniform: scalar-pipe delivery

  // stage layer weights/biases into LDS
  {
    const float* Wp[6] = {W1,W2,W3,W4,W5,W6};
    const float* bp[7] = {b1,b2,b3,b4,b5,b6,b7};
    const int wsz[6] = {4,16,32,64,128,256};
    const int wof[6] = {0,4,20,52,116,244};
    const int bsz[7] = {4,4,8,8,16,16,32};
    const int bof[7] = {0,4,8,16,24,40,56};
    #pragma unroll
    for (int l = 0; l < 6; ++l) {
      for (int k = t; k < wsz[l]; k += T) Wsh[wof[l] + k] = Wp[l][k];
    }
    #pragma unroll
    for (int l = 0; l < 7; ++l) {
      if (t < bsz[l]) bsh[bof[l] + t] = bp[l][t];
    }
  }
  // stage x tile into column slot 1 of each elem (col 0 gets g1 = A@x)
  {
    const float* xg = x + (size_t)blockIdx.x * (EPB*NN);
    if (t < EPB*NN/4) {
      float4 v = ((const float4*)xg)[t];
      int e = t/6, k = t - e*6;
      ((float4*)(gbuf + e*ESTR + CSTR))[k] = v;
    }
  }
  __syncthreads();

  // g1 = A @ x : 384 tasks (e, i); A rows per-lane from global (2.3 KB, L1-hot)
  {
    int e = t & 15, i = t >> 4;          // i in 0..15
    const float4* xv = (const float4*)(gbuf + e*ESTR + CSTR);
    const float4* Ar = (const float4*)(ws + i*NN);
    float acc = 0.f;
    #pragma unroll
    for (int k = 0; k < 6; ++k) {
      float4 a = Ar[k]; float4 v = xv[k];
      acc += a.x*v.x + a.y*v.y + a.z*v.z + a.w*v.w;
    }
    gbuf[e*ESTR + i] = acc;
    if (t < 128) {
      int i2 = 16 + (t >> 4);            // i in 16..23
      const float4* Ar2 = (const float4*)(ws + i2*NN);
      float acc2 = 0.f;
      #pragma unroll
      for (int k = 0; k < 6; ++k) {
        float4 a = Ar2[k]; float4 v = xv[k];
        acc2 += a.x*v.x + a.y*v.y + a.z*v.z + a.w*v.w;
      }
      gbuf[e*ESTR + i2] = acc2;
    }
  }
  __syncthreads();

  merged_layer<1, 4, 4>(ATg, gbuf, Wsh+0,   bsh+0,  t); __syncthreads();
  merged_layer<4, 4, 4>(ATg, gbuf, Wsh+4,   bsh+4,  t); __syncthreads();
  merged_layer<4, 8, 2>(ATg, gbuf, Wsh+20,  bsh+8,  t); __syncthreads();
  merged_layer<8, 8, 2>(ATg, gbuf, Wsh+52,  bsh+16, t); __syncthreads();
  merged_layer<8,16, 1>(ATg, gbuf, Wsh+116, bsh+24, t); __syncthreads();
  merged_layer<16,16,1>(ATg, gbuf, Wsh+244, bsh+40, t); __syncthreads();

  // L7 + composed FC + log_softmax, READ-ONCE 2-col form with row-half passes:
  // thread (e = t>>4, f0 = t&15, f1 = f0+16) reads each g row-half ONCE,
  // computes hA/hB for those 12 rows (6 v2f each — low register pressure),
  // folds the partial P-mix into p, and discards. g read once per elem:
  // 96 ds_read_b128/thread vs round-4's 192 — the kernel's largest DS cut.
  {
    const float* Wc = ws + 576;
    float bc0 = ws[2112], bc1 = ws[2113];
    int e = t >> 4, f0 = t & 15;
    const float* ib = gbuf + e*ESTR;
    float bA = bsh[56 + f0], bB = bsh[56 + f0 + 16];
    v2f p = (v2f){0.f, 0.f};           // (p0, p1)
    #pragma unroll
    for (int half = 0; half < 2; ++half) {
      v2f hA[6], hB[6];
      #pragma unroll
      for (int k = 0; k < 6; ++k) { hA[k] = (v2f){bA, bA}; hB[k] = (v2f){bB, bB}; }
      #pragma unroll
      for (int fi = 0; fi < 16; ++fi) {
        float wa = W7[fi*32 + f0];     // global, L1-cached, coalesced
        float wb = W7[fi*32 + f0 + 16];
        v2f wA2 = (v2f){wa, wa};
        v2f wB2 = (v2f){wb, wb};
        const v4f* c4 = (const v4f*)(ib + fi*CSTR + half*12);
        #pragma unroll
        for (int k = 0; k < 3; ++k) {
          v4f v = c4[k];
          v2f lo = __builtin_shufflevector(v, v, 0, 1);
          v2f hi = __builtin_shufflevector(v, v, 2, 3);
          hA[2*k]   = pkfma(lo, wA2, hA[2*k]);
          hA[2*k+1] = pkfma(hi, wA2, hA[2*k+1]);
          hB[2*k]   = pkfma(lo, wB2, hB[2*k]);
          hB[2*k+1] = pkfma(hi, wB2, hB[2*k+1]);
        }
      }
      #pragma unroll
      for (int k = 0; k < 6; ++k) {
        hA[k] = __builtin_elementwise_max(hA[k], (v2f){0.f, 0.f});
        hB[k] = __builtin_elementwise_max(hB[k], (v2f){0.f, 0.f});
      }
      #pragma unroll
      for (int m = 0; m < 6; ++m) {
        int kg = half*6 + m;           // global row pair: nodes 2kg, 2kg+1
        v2f hpA = hA[m], hpB = hB[m];
        v2f wcA0 = *(const v2f*)(Wc + ((2*kg)*32 + f0)*2);
        v2f wcA1 = *(const v2f*)(Wc + ((2*kg + 1)*32 + f0)*2);
        v2f wcB0 = *(const v2f*)(Wc + ((2*kg)*32 + f0 + 16)*2);
        v2f wcB1 = *(const v2f*)(Wc + ((2*kg + 1)*32 + f0 + 16)*2);
        p = pkfma_b0(wcA0, hpA, p);
        p = pkfma_b1(wcA1, hpA, p);
        p = pkfma_b0(wcB0, hpB, p);
        p = pkfma_b1(wcB1, hpB, p);
      }
    }
    float p0 = p.x, p1 = p.y;
    #pragma unroll
    for (int m = 1; m < 16; m <<= 1) {
      p0 += __shfl_xor(p0, m, 16);
      p1 += __shfl_xor(p1, m, 16);
    }
    if (f0 < 2) {
      float z0 = p0 + bc0, z1 = p1 + bc1;
      float mx = fmaxf(z0, z1);
      float lse = mx + logf(expf(z0 - mx) + expf(z1 - mx));
      int eg = blockIdx.x*EPB + e;
      out[eg*2 + f0] = (f0 == 0 ? z0 : z1) - lse;
    }
  }
}

extern "C" void kernel_launch(void* const* d_in, const int* in_sizes, int n_in,
                              void* d_out, int out_size, void* d_ws, size_t ws_size,
                              hipStream_t stream) {
  const float* x    = (const float*)d_in[0];
  const int*   ei   = (const int*)  d_in[1];
  const float* W1   = (const float*)d_in[2];  const float* b1 = (const float*)d_in[3];
  const float* W2   = (const float*)d_in[4];  const float* b2 = (const float*)d_in[5];
  const float* W3   = (const float*)d_in[6];  const float* b3 = (const float*)d_in[7];
  const float* W4   = (const float*)d_in[8];  const float* b4 = (const float*)d_in[9];
  const float* W5   = (const float*)d_in[10]; const float* b5 = (const float*)d_in[11];
  const float* W6   = (const float*)d_in[12]; const float* b6 = (const float*)d_in[13];
  const float* W7   = (const float*)d_in[14]; const float* b7 = (const float*)d_in[15];
  const float* fcw1 = (const float*)d_in[16]; const float* fcb1 = (const float*)d_in[17];
  const float* fcw2 = (const float*)d_in[18]; const float* fcb2 = (const float*)d_in[19];
  float* out = (float*)d_out;
  float* ws  = (float*)d_ws;
  int ec = in_sizes[1] / 2;        // 96 edges
  int B  = in_sizes[0] / NN;       // 32768

  hipLaunchKernelGGL(prep_kernel, dim3(9), dim3(T), 0, stream,
                     ei, ec, fcw1, fcb1, fcw2, fcb2, ws);
  hipLaunchKernelGGL(gcn_main, dim3(B/EPB), dim3(T), 0, stream,
                     x, ws, W1,b1, W2,b2, W3,b3, W4,b4, W5,b5, W6,b6, W7,b7, out);
}

// Round 11
// 154.138 us; speedup vs baseline: 1.4318x; 1.0060x over previous
//
#include <hip/hip_runtime.h>
#include <math.h>

#define NN   24          // nodes per graph
#define EPB  16          // graph elements per block
#define CSTR 28          // LDS column stride (floats): 24 + 4 pad, 16B aligned
#define ESTR 452         // per-elem stride: 16*28 + 4 → e-stride ≡ 4 banks mod 32
#define T    256
#define AT_OFF 2176      // A^T (24x24) in ws, 16B-aligned float offset

typedef float v2f __attribute__((ext_vector_type(2)));
typedef float v4f __attribute__((ext_vector_type(4)));

// Guaranteed packed math: d = a*b + c on 2xf32 register pairs.
static __device__ __forceinline__ v2f pkfma(v2f a, v2f b, v2f c) {
  asm("v_pk_fma_f32 %0, %1, %2, %0" : "+v"(c) : "v"(a), "v"(b));
  return c;
}
// c += a * broadcast(b.lo)  (src1 low half replicated via op_sel — no splat mov)
static __device__ __forceinline__ v2f pkfma_b0(v2f a, v2f b, v2f c) {
  asm("v_pk_fma_f32 %0, %1, %2, %0 op_sel:[0,0,0] op_sel_hi:[1,0,1]"
      : "+v"(c) : "v"(a), "v"(b));
  return c;
}
// c += a * broadcast(b.hi)
static __device__ __forceinline__ v2f pkfma_b1(v2f a, v2f b, v2f c) {
  asm("v_pk_fma_f32 %0, %1, %2, %0 op_sel:[0,1,0] op_sel_hi:[1,1,1]"
      : "+v"(c) : "v"(a), "v"(b));
  return c;
}
// Same, but a (src0) delivered from an SGPR pair — scalar-pipe operand flow.
// VOP3P allows one SGPR operand; avoids both LDS traffic and s->v movs.
static __device__ __forceinline__ v2f pkfma_sb0(v2f a, v2f b, v2f c) {
  asm("v_pk_fma_f32 %0, %1, %2, %0 op_sel:[0,0,0] op_sel_hi:[1,0,1]"
      : "+v"(c) : "s"(a), "v"(b));
  return c;
}
static __device__ __forceinline__ v2f pkfma_sb1(v2f a, v2f b, v2f c) {
  asm("v_pk_fma_f32 %0, %1, %2, %0 op_sel:[0,1,0] op_sel_hi:[1,1,1]"
      : "+v"(c) : "s"(a), "v"(b));
  return c;
}

// ws layout (floats): [0..575] A(24x24) | [576..2111] Wc(768x2) | [2112..2113] bc(2)
//                     | [2176..2751] AT(24x24)   (assumes ws_size >= 11008 B)

__global__ void prep_kernel(const int* __restrict__ ei, int ec,
                            const float* __restrict__ fcw1, const float* __restrict__ fcb1,
                            const float* __restrict__ fcw2, const float* __restrict__ fcb2,
                            float* __restrict__ ws) {
  int t = threadIdx.x;
  if (blockIdx.x == 0) {
    __shared__ float deg[NN];
    __shared__ float dinv[NN];
    __shared__ float As[NN*NN];
    __shared__ int s_is64;
    if (t == 0) s_is64 = 1;
    if (t < NN) deg[t] = 1.0f;            // self-loop contribution
    for (int k = t; k < NN*NN; k += T) As[k] = 0.0f;
    __syncthreads();
    // dtype sniff: int64 edge_index viewed as int32 has all odd (high) words == 0
    for (int k = t; k < 2*ec; k += T) {
      if (ei[2*k + 1] != 0) atomicExch(&s_is64, 0);
    }
    __syncthreads();
    int is64 = s_is64;
    for (int k = t; k < ec; k += T) {
      int d = is64 ? ei[2*(ec + k)] : ei[ec + k];
      atomicAdd(&deg[d], 1.0f);
    }
    __syncthreads();
    if (t < NN) dinv[t] = 1.0f / sqrtf(deg[t]);
    __syncthreads();
    for (int k = t; k < ec; k += T) {
      int s = is64 ? ei[2*k]        : ei[k];
      int d = is64 ? ei[2*(ec + k)] : ei[ec + k];
      atomicAdd(&As[d*NN + s], dinv[s]*dinv[d]);
    }
    if (t < NN) atomicAdd(&As[t*NN + t], dinv[t]*dinv[t]);  // self loop
    __syncthreads();
    for (int k = t; k < NN*NN; k += T) {
      float a = As[k];
      int r = k / NN, c = k % NN;
      ws[k] = a;                       // A (row-major), used by g1 stage
      ws[AT_OFF + c*NN + r] = a;       // A^T, used by column-form A-mix
    }
    if (t < 2) {
      float acc = fcb2[t];
      for (int k = 0; k < 128; ++k) acc += fcb1[k]*fcw2[k*2 + t];
      ws[2112 + t] = acc;
    }
  } else {
    // Wc = fcw1 @ fcw2 : blocks 1..8 compute 96 rows each (fcw2 transposed in LDS)
    __shared__ __align__(16) float w2t[256];
    for (int k = t; k < 256; k += T) w2t[(k & 1)*128 + (k >> 1)] = fcw2[k];
    __syncthreads();
    int r0 = (blockIdx.x - 1) * 96;
    for (int idx = t; idx < 96*2; idx += T) {
      int r = r0 + (idx >> 1), c = idx & 1;
      const v4f* w1r = (const v4f*)(fcw1 + r*128);
      const v4f* w2v = (const v4f*)(w2t + c*128);
      v4f s = (v4f){0.f, 0.f, 0.f, 0.f};
      #pragma unroll
      for (int k = 0; k < 32; ++k) s = w1r[k]*w2v[k] + s;
      ws[576 + r*2 + c] = (s.x + s.y) + (s.z + s.w);
    }
  }
}

// Merged step (L1-L4): W-mix h col f in 12 v2f (pk-fma), barrier, column-form
// A-mix with ALL A operands via scalar pipe (s_load → "s" src0).
template<int FIN, int FOUT, int SPLIT>
__device__ __forceinline__ void merged_layer(const float* __restrict__ ATg, float* gbuf,
                                             const float* Ws, const float* bs, int t) {
  constexpr int NCOLS = EPB*FOUT;       // 64/64/128/128
  constexpr int CL    = NN/SPLIT;       // 6/6/12/12
  constexpr int NV    = CL/2;
  int col = t & (NCOLS - 1);
  int i0  = __builtin_amdgcn_readfirstlane((t / NCOLS) * CL);  // wave-uniform
  int e = col / FOUT;
  int f = col & (FOUT - 1);
  const float* ib = gbuf + e*ESTR;
  // hoist W column + bias (batched LDS b32 reads, latency overlapped)
  float wcol[FIN];
  #pragma unroll
  for (int fi = 0; fi < FIN; ++fi) wcol[fi] = Ws[fi*FOUT + f];
  float bf = bs[f];
  v2f hh[12];
  #pragma unroll
  for (int k = 0; k < 12; ++k) hh[k] = (v2f){bf, bf};
  #pragma unroll
  for (int fi = 0; fi < FIN; ++fi) {
    v2f w2 = (v2f){wcol[fi], wcol[fi]};
    const v4f* c4 = (const v4f*)(ib + fi*CSTR);
    #pragma unroll
    for (int k = 0; k < 6; ++k) {
      v4f v = c4[k];
      v2f lo = __builtin_shufflevector(v, v, 0, 1);
      v2f hi = __builtin_shufflevector(v, v, 2, 3);
      hh[2*k]   = pkfma(lo, w2, hh[2*k]);
      hh[2*k+1] = pkfma(hi, w2, hh[2*k+1]);
    }
  }
  #pragma unroll
  for (int k = 0; k < 12; ++k)
    hh[k] = __builtin_elementwise_max(hh[k], (v2f){0.f, 0.f});
  __syncthreads();           // all gbuf reads complete before in-place overwrite
  // A-mix, column form over rows i0..i0+CL-1; jp runs over h pairs (elems 0/1)
  float* ob = gbuf + e*ESTR + f*CSTR + i0;
  v2f acc[NV] = {};
  #pragma unroll
  for (int jp = 0; jp < 12; ++jp) {
    v2f hp = hh[jp];
    const v2f* gA = (const v2f*)(ATg + (2*jp)*NN + i0);      // uniform → s_load
    const v2f* gB = (const v2f*)(ATg + (2*jp + 1)*NN + i0);
    #pragma unroll
    for (int k = 0; k < NV; ++k) {
      acc[k] = pkfma_sb0(gA[k], hp, acc[k]);
      acc[k] = pkfma_sb1(gB[k], hp, acc[k]);
    }
  }
  #pragma unroll
  for (int k = 0; k < NV; ++k) *(v2f*)(ob + 2*k) = acc[k];
}

// L5/L6 (FOUT=16) with fi-SPLIT LANE PAIRING: lanes (l, l+32) serve the same
// (e, f-pair). Lane l sums fi in [0,FIN/2) — pA targets its OWN column
// (fcol = f_lo + 8*hi), pB targets the partner's column. One cross-lane add
// h = pA + shfl_xor(pB, 32) completes both columns. W-mix ds_read count HALVES
// (96→48 for L6) for +24 b32 shuffles; register peak unchanged (pA+pB = 48
// VGPRs = round-10's hh+acc profile). A-mix identical to SPLIT=1 (SMEM pipe).
template<int FIN>
__device__ __forceinline__ void fused16s(const float* __restrict__ ATg, float* gbuf,
                                         const float* Ws, const float* bs, int t) {
  int lane = t & 63, w = t >> 6;
  int q = w*32 + (lane & 31);           // pair index: 32 pairs/wave, 128 total
  int e = q >> 3, f_lo = q & 7;
  int hi = lane >> 5;                   // 0 = lo half, 1 = hi half
  int fcol = f_lo + (hi << 3);          // own output column
  int fother = f_lo + ((1 - hi) << 3);  // partner's column
  int fib = hi * (FIN/2);               // own fi range base
  const float* ib = gbuf + e*ESTR;
  float bf = bs[fcol];
  v2f pA[12], pB[12];
  #pragma unroll
  for (int k = 0; k < 12; ++k) { pA[k] = (v2f){bf, bf}; pB[k] = (v2f){0.f, 0.f}; }
  #pragma unroll
  for (int fi = 0; fi < FIN/2; ++fi) {
    int fe = fi + fib;
    float wa = Ws[fe*16 + fcol];
    float wb = Ws[fe*16 + fother];
    v2f wA2 = (v2f){wa, wa};
    v2f wB2 = (v2f){wb, wb};
    const v4f* c4 = (const v4f*)(ib + fe*CSTR);
    #pragma unroll
    for (int k = 0; k < 6; ++k) {
      v4f v = c4[k];
      v2f lo = __builtin_shufflevector(v, v, 0, 1);
      v2f hh = __builtin_shufflevector(v, v, 2, 3);
      pA[2*k]   = pkfma(lo, wA2, pA[2*k]);
      pA[2*k+1] = pkfma(hh, wA2, pA[2*k+1]);
      pB[2*k]   = pkfma(lo, wB2, pB[2*k]);
      pB[2*k+1] = pkfma(hh, wB2, pB[2*k+1]);
    }
  }
  // cross-lane completion: partner's pB is the missing fi-half of my column
  v2f h[12];
  #pragma unroll
  for (int k = 0; k < 12; ++k) {
    v2f r;
    r.x = __shfl_xor(pB[k].x, 32);
    r.y = __shfl_xor(pB[k].y, 32);
    h[k] = __builtin_elementwise_max(pA[k] + r, (v2f){0.f, 0.f});
  }
  __syncthreads();           // all gbuf reads complete before in-place overwrite
  // A-mix, full column (i0 = 0, CL = 24), scalar-pipe A operands
  float* ob = gbuf + e*ESTR + fcol*CSTR;
  v2f acc[12] = {};
  #pragma unroll
  for (int jp = 0; jp < 12; ++jp) {
    v2f hp = h[jp];
    const v2f* gA = (const v2f*)(ATg + (2*jp)*NN);           // uniform → s_load
    const v2f* gB = (const v2f*)(ATg + (2*jp + 1)*NN);
    #pragma unroll
    for (int k = 0; k < 12; ++k) {
      acc[k] = pkfma_sb0(gA[k], hp, acc[k]);
      acc[k] = pkfma_sb1(gB[k], hp, acc[k]);
    }
  }
  #pragma unroll
  for (int k = 0; k < 12; ++k) *(v2f*)(ob + 2*k) = acc[k];
}

__global__ __launch_bounds__(256, 4) void gcn_main(
    const float* __restrict__ x, const float* __restrict__ ws,
    const float* __restrict__ W1, const float* __restrict__ b1,
    const float* __restrict__ W2, const float* __restrict__ b2,
    const float* __restrict__ W3, const float* __restrict__ b3,
    const float* __restrict__ W4, const float* __restrict__ b4,
    const float* __restrict__ W5, const float* __restrict__ b5,
    const float* __restrict__ W6, const float* __restrict__ b6,
    const float* __restrict__ W7, const float* __restrict__ b7,
    float* __restrict__ out) {
  __shared__ __align__(16) float gbuf[EPB*ESTR];  // 28928 B, single in-place buffer
  __shared__ float Wsh[500];                      // W1..W6; W7 read from global/L1
  __shared__ __align__(16) float bsh[88];
  int t = threadIdx.x;
  const float* ATg = ws + AT_OFF;       // wave-uniform: scalar-pipe delivery

  // stage layer weights/biases into LDS
  {
    const float* Wp[6] = {W1,W2,W3,W4,W5,W6};
    const float* bp[7] = {b1,b2,b3,b4,b5,b6,b7};
    const int wsz[6] = {4,16,32,64,128,256};
    const int wof[6] = {0,4,20,52,116,244};
    const int bsz[7] = {4,4,8,8,16,16,32};
    const int bof[7] = {0,4,8,16,24,40,56};
    #pragma unroll
    for (int l = 0; l < 6; ++l) {
      for (int k = t; k < wsz[l]; k += T) Wsh[wof[l] + k] = Wp[l][k];
    }
    #pragma unroll
    for (int l = 0; l < 7; ++l) {
      if (t < bsz[l]) bsh[bof[l] + t] = bp[l][t];
    }
  }
  // stage x tile into column slot 1 of each elem (col 0 gets g1 = A@x)
  {
    const float* xg = x + (size_t)blockIdx.x * (EPB*NN);
    if (t < EPB*NN/4) {
      float4 v = ((const float4*)xg)[t];
      int e = t/6, k = t - e*6;
      ((float4*)(gbuf + e*ESTR + CSTR))[k] = v;
    }
  }
  __syncthreads();

  // g1 = A @ x : 384 tasks (e, i); A rows per-lane from global (2.3 KB, L1-hot)
  {
    int e = t & 15, i = t >> 4;          // i in 0..15
    const float4* xv = (const float4*)(gbuf + e*ESTR + CSTR);
    const float4* Ar = (const float4*)(ws + i*NN);
    float acc = 0.f;
    #pragma unroll
    for (int k = 0; k < 6; ++k) {
      float4 a = Ar[k]; float4 v = xv[k];
      acc += a.x*v.x + a.y*v.y + a.z*v.z + a.w*v.w;
    }
    gbuf[e*ESTR + i] = acc;
    if (t < 128) {
      int i2 = 16 + (t >> 4);            // i in 16..23
      const float4* Ar2 = (const float4*)(ws + i2*NN);
      float acc2 = 0.f;
      #pragma unroll
      for (int k = 0; k < 6; ++k) {
        float4 a = Ar2[k]; float4 v = xv[k];
        acc2 += a.x*v.x + a.y*v.y + a.z*v.z + a.w*v.w;
      }
      gbuf[e*ESTR + i2] = acc2;
    }
  }
  __syncthreads();

  merged_layer<1, 4, 4>(ATg, gbuf, Wsh+0,   bsh+0,  t); __syncthreads();
  merged_layer<4, 4, 4>(ATg, gbuf, Wsh+4,   bsh+4,  t); __syncthreads();
  merged_layer<4, 8, 2>(ATg, gbuf, Wsh+20,  bsh+8,  t); __syncthreads();
  merged_layer<8, 8, 2>(ATg, gbuf, Wsh+52,  bsh+16, t); __syncthreads();
  fused16s<8> (ATg, gbuf, Wsh+116, bsh+24, t);          __syncthreads();
  fused16s<16>(ATg, gbuf, Wsh+244, bsh+40, t);          __syncthreads();

  // L7 + composed FC + log_softmax, READ-ONCE 2-col form with row-half passes:
  // thread (e = t>>4, f0 = t&15, f1 = f0+16) reads each g row-half ONCE,
  // computes hA/hB for those 12 rows (6 v2f each — low register pressure),
  // folds the partial P-mix into p, and discards. g read once per elem:
  // 96 ds_read_b128/thread vs round-4's 192 — the kernel's largest DS cut.
  {
    const float* Wc = ws + 576;
    float bc0 = ws[2112], bc1 = ws[2113];
    int e = t >> 4, f0 = t & 15;
    const float* ib = gbuf + e*ESTR;
    float bA = bsh[56 + f0], bB = bsh[56 + f0 + 16];
    v2f p = (v2f){0.f, 0.f};           // (p0, p1)
    #pragma unroll
    for (int half = 0; half < 2; ++half) {
      v2f hA[6], hB[6];
      #pragma unroll
      for (int k = 0; k < 6; ++k) { hA[k] = (v2f){bA, bA}; hB[k] = (v2f){bB, bB}; }
      #pragma unroll
      for (int fi = 0; fi < 16; ++fi) {
        float wa = W7[fi*32 + f0];     // global, L1-cached, coalesced
        float wb = W7[fi*32 + f0 + 16];
        v2f wA2 = (v2f){wa, wa};
        v2f wB2 = (v2f){wb, wb};
        const v4f* c4 = (const v4f*)(ib + fi*CSTR + half*12);
        #pragma unroll
        for (int k = 0; k < 3; ++k) {
          v4f v = c4[k];
          v2f lo = __builtin_shufflevector(v, v, 0, 1);
          v2f hi = __builtin_shufflevector(v, v, 2, 3);
          hA[2*k]   = pkfma(lo, wA2, hA[2*k]);
          hA[2*k+1] = pkfma(hi, wA2, hA[2*k+1]);
          hB[2*k]   = pkfma(lo, wB2, hB[2*k]);
          hB[2*k+1] = pkfma(hi, wB2, hB[2*k+1]);
        }
      }
      #pragma unroll
      for (int k = 0; k < 6; ++k) {
        hA[k] = __builtin_elementwise_max(hA[k], (v2f){0.f, 0.f});
        hB[k] = __builtin_elementwise_max(hB[k], (v2f){0.f, 0.f});
      }
      #pragma unroll
      for (int m = 0; m < 6; ++m) {
        int kg = half*6 + m;           // global row pair: nodes 2kg, 2kg+1
        v2f hpA = hA[m], hpB = hB[m];
        v2f wcA0 = *(const v2f*)(Wc + ((2*kg)*32 + f0)*2);
        v2f wcA1 = *(const v2f*)(Wc + ((2*kg + 1)*32 + f0)*2);
        v2f wcB0 = *(const v2f*)(Wc + ((2*kg)*32 + f0 + 16)*2);
        v2f wcB1 = *(const v2f*)(Wc + ((2*kg + 1)*32 + f0 + 16)*2);
        p = pkfma_b0(wcA0, hpA, p);
        p = pkfma_b1(wcA1, hpA, p);
        p = pkfma_b0(wcB0, hpB, p);
        p = pkfma_b1(wcB1, hpB, p);
      }
    }
    float p0 = p.x, p1 = p.y;
    #pragma unroll
    for (int m = 1; m < 16; m <<= 1) {
      p0 += __shfl_xor(p0, m, 16);
      p1 += __shfl_xor(p1, m, 16);
    }
    if (f0 < 2) {
      float z0 = p0 + bc0, z1 = p1 + bc1;
      float mx = fmaxf(z0, z1);
      float lse = mx + logf(expf(z0 - mx) + expf(z1 - mx));
      int eg = blockIdx.x*EPB + e;
      out[eg*2 + f0] = (f0 == 0 ? z0 : z1) - lse;
    }
  }
}

extern "C" void kernel_launch(void* const* d_in, const int* in_sizes, int n_in,
                              void* d_out, int out_size, void* d_ws, size_t ws_size,
                              hipStream_t stream) {
  const float* x    = (const float*)d_in[0];
  const int*   ei   = (const int*)  d_in[1];
  const float* W1   = (const float*)d_in[2];  const float* b1 = (const float*)d_in[3];
  const float* W2   = (const float*)d_in[4];  const float* b2 = (const float*)d_in[5];
  const float* W3   = (const float*)d_in[6];  const float* b3 = (const float*)d_in[7];
  const float* W4   = (const float*)d_in[8];  const float* b4 = (const float*)d_in[9];
  const float* W5   = (const float*)d_in[10]; const float* b5 = (const float*)d_in[11];
  const float* W6   = (const float*)d_in[12]; const float* b6 = (const float*)d_in[13];
  const float* W7   = (const float*)d_in[14]; const float* b7 = (const float*)d_in[15];
  const float* fcw1 = (const float*)d_in[16]; const float* fcb1 = (const float*)d_in[17];
  const float* fcw2 = (const float*)d_in[18]; const float* fcb2 = (const float*)d_in[19];
  float* out = (float*)d_out;
  float* ws  = (float*)d_ws;
  int ec = in_sizes[1] / 2;        // 96 edges
  int B  = in_sizes[0] / NN;       // 32768

  hipLaunchKernelGGL(prep_kernel, dim3(9), dim3(T), 0, stream,
                     ei, ec, fcw1, fcb1, fcw2, fcb2, ws);
  hipLaunchKernelGGL(gcn_main, dim3(B/EPB), dim3(T), 0, stream,
                     x, ws, W1,b1, W2,b2, W3,b3, W4,b4, W5,b5, W6,b6, W7,b7, out);
}

// Round 12
// 153.131 us; speedup vs baseline: 1.4412x; 1.0066x over previous
//
#include <hip/hip_runtime.h>
#include <math.h>

#define NN   24          // nodes per graph
#define EPB  16          // graph elements per block
#define CSTR 28          // LDS column stride (floats): 24 + 4 pad, 16B aligned
#define ESTR 452         // per-elem stride: 16*28 + 4 → e-stride ≡ 4 banks mod 32
#define T    256
#define AT_OFF  2176     // A^T (24x24) in ws, 16B-aligned float offset
#define W7T_OFF 2752     // W7 transposed [32][16] in ws

typedef float v2f __attribute__((ext_vector_type(2)));
typedef float v4f __attribute__((ext_vector_type(4)));

static __device__ __forceinline__ v2f vlo(v4f v){return __builtin_shufflevector(v,v,0,1);}
static __device__ __forceinline__ v2f vhi(v4f v){return __builtin_shufflevector(v,v,2,3);}

// Guaranteed packed math: d = a*b + c on 2xf32 register pairs.
static __device__ __forceinline__ v2f pkfma(v2f a, v2f b, v2f c) {
  asm("v_pk_fma_f32 %0, %1, %2, %0" : "+v"(c) : "v"(a), "v"(b));
  return c;
}
// c += a * broadcast(b.lo)  (src1 low half replicated via op_sel — no splat mov)
static __device__ __forceinline__ v2f pkfma_b0(v2f a, v2f b, v2f c) {
  asm("v_pk_fma_f32 %0, %1, %2, %0 op_sel:[0,0,0] op_sel_hi:[1,0,1]"
      : "+v"(c) : "v"(a), "v"(b));
  return c;
}
// c += a * broadcast(b.hi)
static __device__ __forceinline__ v2f pkfma_b1(v2f a, v2f b, v2f c) {
  asm("v_pk_fma_f32 %0, %1, %2, %0 op_sel:[0,1,0] op_sel_hi:[1,1,1]"
      : "+v"(c) : "v"(a), "v"(b));
  return c;
}
// Same, but a (src0) delivered from an SGPR pair — scalar-pipe operand flow.
static __device__ __forceinline__ v2f pkfma_sb0(v2f a, v2f b, v2f c) {
  asm("v_pk_fma_f32 %0, %1, %2, %0 op_sel:[0,0,0] op_sel_hi:[1,0,1]"
      : "+v"(c) : "s"(a), "v"(b));
  return c;
}
static __device__ __forceinline__ v2f pkfma_sb1(v2f a, v2f b, v2f c) {
  asm("v_pk_fma_f32 %0, %1, %2, %0 op_sel:[0,1,0] op_sel_hi:[1,1,1]"
      : "+v"(c) : "s"(a), "v"(b));
  return c;
}
// Multiplicative seeds: d = a * broadcast(b.lo/hi) — replaces zero-init + fma.
static __device__ __forceinline__ v2f pkmul_b0(v2f a, v2f b) {
  v2f d;
  asm("v_pk_mul_f32 %0, %1, %2 op_sel:[0,0] op_sel_hi:[1,0]"
      : "=v"(d) : "v"(a), "v"(b));
  return d;
}
static __device__ __forceinline__ v2f pkmul_sb0(v2f a, v2f b) {
  v2f d;
  asm("v_pk_mul_f32 %0, %1, %2 op_sel:[0,0] op_sel_hi:[1,0]"
      : "=v"(d) : "s"(a), "v"(b));
  return d;
}

// ws layout (floats): [0..575] A(24x24) | [576..2111] Wc(768x2) | [2112..2113] bc(2)
//   | [2176..2751] AT(24x24) | [2752..3263] W7T(32x16)  (assumes ws_size >= 13056 B)

__global__ void prep_kernel(const int* __restrict__ ei, int ec,
                            const float* __restrict__ fcw1, const float* __restrict__ fcb1,
                            const float* __restrict__ fcw2, const float* __restrict__ fcb2,
                            const float* __restrict__ W7, float* __restrict__ ws) {
  int t = threadIdx.x;
  if (blockIdx.x == 0) {
    __shared__ float deg[NN];
    __shared__ float dinv[NN];
    __shared__ float As[NN*NN];
    __shared__ int s_is64;
    if (t == 0) s_is64 = 1;
    if (t < NN) deg[t] = 1.0f;            // self-loop contribution
    for (int k = t; k < NN*NN; k += T) As[k] = 0.0f;
    __syncthreads();
    // dtype sniff: int64 edge_index viewed as int32 has all odd (high) words == 0
    for (int k = t; k < 2*ec; k += T) {
      if (ei[2*k + 1] != 0) atomicExch(&s_is64, 0);
    }
    __syncthreads();
    int is64 = s_is64;
    for (int k = t; k < ec; k += T) {
      int d = is64 ? ei[2*(ec + k)] : ei[ec + k];
      atomicAdd(&deg[d], 1.0f);
    }
    __syncthreads();
    if (t < NN) dinv[t] = 1.0f / sqrtf(deg[t]);
    __syncthreads();
    for (int k = t; k < ec; k += T) {
      int s = is64 ? ei[2*k]        : ei[k];
      int d = is64 ? ei[2*(ec + k)] : ei[ec + k];
      atomicAdd(&As[d*NN + s], dinv[s]*dinv[d]);
    }
    if (t < NN) atomicAdd(&As[t*NN + t], dinv[t]*dinv[t]);  // self loop
    __syncthreads();
    for (int k = t; k < NN*NN; k += T) {
      float a = As[k];
      int r = k / NN, c = k % NN;
      ws[k] = a;                       // A (row-major), used by g1 stage
      ws[AT_OFF + c*NN + r] = a;       // A^T, used by column-form A-mix
    }
    // W7 transposed: W7T[f][fi] = W7[fi][f]  (pairs (fi,fi+1) become contiguous)
    for (int k = t; k < 512; k += T) {
      int f = k >> 4, fi = k & 15;
      ws[W7T_OFF + k] = W7[fi*32 + f];
    }
    if (t < 2) {
      float acc = fcb2[t];
      for (int k = 0; k < 128; ++k) acc += fcb1[k]*fcw2[k*2 + t];
      ws[2112 + t] = acc;
    }
  } else {
    // Wc = fcw1 @ fcw2 : blocks 1..8 compute 96 rows each (fcw2 transposed in LDS)
    __shared__ __align__(16) float w2t[256];
    for (int k = t; k < 256; k += T) w2t[(k & 1)*128 + (k >> 1)] = fcw2[k];
    __syncthreads();
    int r0 = (blockIdx.x - 1) * 96;
    for (int idx = t; idx < 96*2; idx += T) {
      int r = r0 + (idx >> 1), c = idx & 1;
      const v4f* w1r = (const v4f*)(fcw1 + r*128);
      const v4f* w2v = (const v4f*)(w2t + c*128);
      v4f s = (v4f){0.f, 0.f, 0.f, 0.f};
      #pragma unroll
      for (int k = 0; k < 32; ++k) s = w1r[k]*w2v[k] + s;
      ws[576 + r*2 + c] = (s.x + s.y) + (s.z + s.w);
    }
  }
}

// Merged step (L1-L4): W-mix h col f in 12 v2f via op_sel-broadcast pk-fma with
// TRANSPOSED weights ([FOUT][FIN] in LDS → weight pairs load as one v2f, zero
// splat movs). Barrier, then column-form A-mix with A operands via scalar pipe
// (s_load → "s" src0), seeded by v_pk_mul (no zero-init movs).
template<int FIN, int FOUT, int SPLIT>
__device__ __forceinline__ void merged_layer(const float* __restrict__ ATg, float* gbuf,
                                             const float* Ws, const float* bs, int t) {
  constexpr int NCOLS = EPB*FOUT;       // 64/64/128/128
  constexpr int CL    = NN/SPLIT;       // 6/6/12/12
  constexpr int NV    = CL/2;
  int col = t & (NCOLS - 1);
  int i0  = __builtin_amdgcn_readfirstlane((t / NCOLS) * CL);  // wave-uniform
  int e = col / FOUT;
  int f = col & (FOUT - 1);
  const float* ib = gbuf + e*ESTR;
  float bf = bs[f];
  v2f hh[12];
  #pragma unroll
  for (int k = 0; k < 12; ++k) hh[k] = (v2f){bf, bf};
  if constexpr (FIN == 1) {
    float w = Ws[f];                    // [FOUT][1] transposed == linear
    v2f w2 = (v2f){w, w};
    const v4f* c4 = (const v4f*)ib;
    #pragma unroll
    for (int k = 0; k < 6; ++k) {
      v4f v = c4[k];
      hh[2*k]   = pkfma(vlo(v), w2, hh[2*k]);
      hh[2*k+1] = pkfma(vhi(v), w2, hh[2*k+1]);
    }
  } else {
    #pragma unroll
    for (int fp = 0; fp < FIN/2; ++fp) {
      v2f wp = *(const v2f*)(Ws + f*FIN + 2*fp);   // (w[2fp], w[2fp+1])
      const v4f* cA = (const v4f*)(ib + (2*fp)*CSTR);
      const v4f* cB = (const v4f*)(ib + (2*fp+1)*CSTR);
      #pragma unroll
      for (int k = 0; k < 6; ++k) {
        v4f vA = cA[k], vB = cB[k];
        hh[2*k]   = pkfma_b0(vlo(vA), wp, hh[2*k]);
        hh[2*k+1] = pkfma_b0(vhi(vA), wp, hh[2*k+1]);
        hh[2*k]   = pkfma_b1(vlo(vB), wp, hh[2*k]);
        hh[2*k+1] = pkfma_b1(vhi(vB), wp, hh[2*k+1]);
      }
    }
  }
  #pragma unroll
  for (int k = 0; k < 12; ++k)
    hh[k] = __builtin_elementwise_max(hh[k], (v2f){0.f, 0.f});
  __syncthreads();           // all gbuf reads complete before in-place overwrite
  // A-mix, column form over rows i0..i0+CL-1; jp runs over h pairs; mul seed.
  float* ob = gbuf + e*ESTR + f*CSTR + i0;
  v2f acc[NV];
  {
    v2f hp = hh[0];
    const v2f* gA = (const v2f*)(ATg + i0);
    const v2f* gB = (const v2f*)(ATg + NN + i0);
    #pragma unroll
    for (int k = 0; k < NV; ++k) {
      acc[k] = pkmul_sb0(gA[k], hp);
      acc[k] = pkfma_sb1(gB[k], hp, acc[k]);
    }
  }
  #pragma unroll
  for (int jp = 1; jp < 12; ++jp) {
    v2f hp = hh[jp];
    const v2f* gA = (const v2f*)(ATg + (2*jp)*NN + i0);      // uniform → s_load
    const v2f* gB = (const v2f*)(ATg + (2*jp + 1)*NN + i0);
    #pragma unroll
    for (int k = 0; k < NV; ++k) {
      acc[k] = pkfma_sb0(gA[k], hp, acc[k]);
      acc[k] = pkfma_sb1(gB[k], hp, acc[k]);
    }
  }
  #pragma unroll
  for (int k = 0; k < NV; ++k) *(v2f*)(ob + 2*k) = acc[k];
}

// L5/L6 (FOUT=16) with fi-SPLIT LANE PAIRING (round 11) + transposed packed
// weights + pk_mul seeds. Lanes (l, l+32) serve the same (e, f-pair); each
// sums its fi-half for both columns; h = pA + shfl_xor(pB, 32).
template<int FIN>
__device__ __forceinline__ void fused16s(const float* __restrict__ ATg, float* gbuf,
                                         const float* Ws, const float* bs, int t) {
  int lane = t & 63, w = t >> 6;
  int q = w*32 + (lane & 31);           // pair index: 32 pairs/wave, 128 total
  int e = q >> 3, f_lo = q & 7;
  int hi = lane >> 5;                   // 0 = lo half, 1 = hi half
  int fcol = f_lo + (hi << 3);          // own output column
  int fother = f_lo + ((1 - hi) << 3);  // partner's column
  int fib = hi * (FIN/2);               // own fi range base
  const float* ib = gbuf + e*ESTR;
  float bf = bs[fcol];
  v2f pA[12], pB[12];
  #pragma unroll
  for (int k = 0; k < 12; ++k) pA[k] = (v2f){bf, bf};
  // fp = 0: pB seeded by pk_mul (no zero-init)
  {
    int fe = fib;
    v2f wpA = *(const v2f*)(Ws + fcol*FIN + fe);
    v2f wpB = *(const v2f*)(Ws + fother*FIN + fe);
    const v4f* cA = (const v4f*)(ib + fe*CSTR);
    const v4f* cB = (const v4f*)(ib + (fe+1)*CSTR);
    #pragma unroll
    for (int k = 0; k < 6; ++k) {
      v4f vA = cA[k], vB = cB[k];
      v2f alo = vlo(vA), ahi = vhi(vA), blo = vlo(vB), bhi = vhi(vB);
      pA[2*k]   = pkfma_b0(alo, wpA, pA[2*k]);
      pA[2*k+1] = pkfma_b0(ahi, wpA, pA[2*k+1]);
      pB[2*k]   = pkmul_b0(alo, wpB);
      pB[2*k+1] = pkmul_b0(ahi, wpB);
      pA[2*k]   = pkfma_b1(blo, wpA, pA[2*k]);
      pA[2*k+1] = pkfma_b1(bhi, wpA, pA[2*k+1]);
      pB[2*k]   = pkfma_b1(blo, wpB, pB[2*k]);
      pB[2*k+1] = pkfma_b1(bhi, wpB, pB[2*k+1]);
    }
  }
  #pragma unroll
  for (int fp = 1; fp < FIN/4; ++fp) {
    int fe = 2*fp + fib;
    v2f wpA = *(const v2f*)(Ws + fcol*FIN + fe);
    v2f wpB = *(const v2f*)(Ws + fother*FIN + fe);
    const v4f* cA = (const v4f*)(ib + fe*CSTR);
    const v4f* cB = (const v4f*)(ib + (fe+1)*CSTR);
    #pragma unroll
    for (int k = 0; k < 6; ++k) {
      v4f vA = cA[k], vB = cB[k];
      v2f alo = vlo(vA), ahi = vhi(vA), blo = vlo(vB), bhi = vhi(vB);
      pA[2*k]   = pkfma_b0(alo, wpA, pA[2*k]);
      pA[2*k+1] = pkfma_b0(ahi, wpA, pA[2*k+1]);
      pB[2*k]   = pkfma_b0(alo, wpB, pB[2*k]);
      pB[2*k+1] = pkfma_b0(ahi, wpB, pB[2*k+1]);
      pA[2*k]   = pkfma_b1(blo, wpA, pA[2*k]);
      pA[2*k+1] = pkfma_b1(bhi, wpA, pA[2*k+1]);
      pB[2*k]   = pkfma_b1(blo, wpB, pB[2*k]);
      pB[2*k+1] = pkfma_b1(bhi, wpB, pB[2*k+1]);
    }
  }
  // cross-lane completion: partner's pB is the missing fi-half of my column
  v2f h[12];
  #pragma unroll
  for (int k = 0; k < 12; ++k) {
    v2f r;
    r.x = __shfl_xor(pB[k].x, 32);
    r.y = __shfl_xor(pB[k].y, 32);
    h[k] = __builtin_elementwise_max(pA[k] + r, (v2f){0.f, 0.f});
  }
  __syncthreads();           // all gbuf reads complete before in-place overwrite
  // A-mix, full column (i0 = 0, CL = 24), scalar-pipe A operands, mul seed
  float* ob = gbuf + e*ESTR + fcol*CSTR;
  v2f acc[12];
  {
    v2f hp = h[0];
    const v2f* gA = (const v2f*)(ATg);
    const v2f* gB = (const v2f*)(ATg + NN);
    #pragma unroll
    for (int k = 0; k < 12; ++k) {
      acc[k] = pkmul_sb0(gA[k], hp);
      acc[k] = pkfma_sb1(gB[k], hp, acc[k]);
    }
  }
  #pragma unroll
  for (int jp = 1; jp < 12; ++jp) {
    v2f hp = h[jp];
    const v2f* gA = (const v2f*)(ATg + (2*jp)*NN);           // uniform → s_load
    const v2f* gB = (const v2f*)(ATg + (2*jp + 1)*NN);
    #pragma unroll
    for (int k = 0; k < 12; ++k) {
      acc[k] = pkfma_sb0(gA[k], hp, acc[k]);
      acc[k] = pkfma_sb1(gB[k], hp, acc[k]);
    }
  }
  #pragma unroll
  for (int k = 0; k < 12; ++k) *(v2f*)(ob + 2*k) = acc[k];
}

__global__ __launch_bounds__(256, 4) void gcn_main(
    const float* __restrict__ x, const float* __restrict__ ws,
    const float* __restrict__ W1, const float* __restrict__ b1,
    const float* __restrict__ W2, const float* __restrict__ b2,
    const float* __restrict__ W3, const float* __restrict__ b3,
    const float* __restrict__ W4, const float* __restrict__ b4,
    const float* __restrict__ W5, const float* __restrict__ b5,
    const float* __restrict__ W6, const float* __restrict__ b6,
    const float* __restrict__ W7, const float* __restrict__ b7,
    float* __restrict__ out) {
  __shared__ __align__(16) float gbuf[EPB*ESTR];  // 28928 B, single in-place buffer
  __shared__ float Wsh[500];                      // W1..W6 TRANSPOSED [FOUT][FIN]
  __shared__ __align__(16) float bsh[88];
  int t = threadIdx.x;
  const float* ATg = ws + AT_OFF;       // wave-uniform: scalar-pipe delivery

  // stage layer weights (transposed) / biases into LDS
  {
    const float* Wp[6] = {W1,W2,W3,W4,W5,W6};
    const float* bp[7] = {b1,b2,b3,b4,b5,b6,b7};
    const int wsz[6]   = {4,16,32,64,128,256};
    const int wof[6]   = {0,4,20,52,116,244};
    const int fouts[6] = {4,4,8,8,16,16};
    const int bsz[7] = {4,4,8,8,16,16,32};
    const int bof[7] = {0,4,8,16,24,40,56};
    #pragma unroll
    for (int l = 0; l < 6; ++l) {
      int FO = fouts[l], FI = wsz[l]/FO;
      for (int k = t; k < wsz[l]; k += T) {
        int fi = k / FO, f = k - fi*FO;
        Wsh[wof[l] + f*FI + fi] = Wp[l][k];
      }
    }
    #pragma unroll
    for (int l = 0; l < 7; ++l) {
      if (t < bsz[l]) bsh[bof[l] + t] = bp[l][t];
    }
  }
  // stage x tile into column slot 1 of each elem (col 0 gets g1 = A@x)
  {
    const float* xg = x + (size_t)blockIdx.x * (EPB*NN);
    if (t < EPB*NN/4) {
      float4 v = ((const float4*)xg)[t];
      int e = t/6, k = t - e*6;
      ((float4*)(gbuf + e*ESTR + CSTR))[k] = v;
    }
  }
  __syncthreads();

  // g1 = A @ x : 384 tasks (e, i); A rows per-lane from global (2.3 KB, L1-hot)
  {
    int e = t & 15, i = t >> 4;          // i in 0..15
    const float4* xv = (const float4*)(gbuf + e*ESTR + CSTR);
    const float4* Ar = (const float4*)(ws + i*NN);
    float acc = 0.f;
    #pragma unroll
    for (int k = 0; k < 6; ++k) {
      float4 a = Ar[k]; float4 v = xv[k];
      acc += a.x*v.x + a.y*v.y + a.z*v.z + a.w*v.w;
    }
    gbuf[e*ESTR + i] = acc;
    if (t < 128) {
      int i2 = 16 + (t >> 4);            // i in 16..23
      const float4* Ar2 = (const float4*)(ws + i2*NN);
      float acc2 = 0.f;
      #pragma unroll
      for (int k = 0; k < 6; ++k) {
        float4 a = Ar2[k]; float4 v = xv[k];
        acc2 += a.x*v.x + a.y*v.y + a.z*v.z + a.w*v.w;
      }
      gbuf[e*ESTR + i2] = acc2;
    }
  }
  __syncthreads();

  merged_layer<1, 4, 4>(ATg, gbuf, Wsh+0,   bsh+0,  t); __syncthreads();
  merged_layer<4, 4, 4>(ATg, gbuf, Wsh+4,   bsh+4,  t); __syncthreads();
  merged_layer<4, 8, 2>(ATg, gbuf, Wsh+20,  bsh+8,  t); __syncthreads();
  merged_layer<8, 8, 2>(ATg, gbuf, Wsh+52,  bsh+16, t); __syncthreads();
  fused16s<8> (ATg, gbuf, Wsh+116, bsh+24, t);          __syncthreads();
  fused16s<16>(ATg, gbuf, Wsh+244, bsh+40, t);          __syncthreads();

  // L7 + composed FC + log_softmax, READ-ONCE 2-col form with row-half passes
  // and TRANSPOSED W7 (pairs → op_sel broadcast, zero splats).
  {
    const float* Wc  = ws + 576;
    const float* W7T = ws + W7T_OFF;     // [32][16]
    float bc0 = ws[2112], bc1 = ws[2113];
    int e = t >> 4, f0 = t & 15;
    const float* ib = gbuf + e*ESTR;
    float bA = bsh[56 + f0], bB = bsh[56 + f0 + 16];
    v2f p = (v2f){0.f, 0.f};           // (p0, p1)
    #pragma unroll
    for (int half = 0; half < 2; ++half) {
      v2f hA[6], hB[6];
      #pragma unroll
      for (int k = 0; k < 6; ++k) { hA[k] = (v2f){bA, bA}; hB[k] = (v2f){bB, bB}; }
      #pragma unroll
      for (int fp = 0; fp < 8; ++fp) {
        v2f wpA = *(const v2f*)(W7T + f0*16 + 2*fp);        // L1-cached
        v2f wpB = *(const v2f*)(W7T + (f0 + 16)*16 + 2*fp);
        const v4f* cA = (const v4f*)(ib + (2*fp)*CSTR + half*12);
        const v4f* cB = (const v4f*)(ib + (2*fp+1)*CSTR + half*12);
        #pragma unroll
        for (int k = 0; k < 3; ++k) {
          v4f vA = cA[k], vB = cB[k];
          v2f alo = vlo(vA), ahi = vhi(vA), blo = vlo(vB), bhi = vhi(vB);
          hA[2*k]   = pkfma_b0(alo, wpA, hA[2*k]);
          hA[2*k+1] = pkfma_b0(ahi, wpA, hA[2*k+1]);
          hB[2*k]   = pkfma_b0(alo, wpB, hB[2*k]);
          hB[2*k+1] = pkfma_b0(ahi, wpB, hB[2*k+1]);
          hA[2*k]   = pkfma_b1(blo, wpA, hA[2*k]);
          hA[2*k+1] = pkfma_b1(bhi, wpA, hA[2*k+1]);
          hB[2*k]   = pkfma_b1(blo, wpB, hB[2*k]);
          hB[2*k+1] = pkfma_b1(bhi, wpB, hB[2*k+1]);
        }
      }
      #pragma unroll
      for (int k = 0; k < 6; ++k) {
        hA[k] = __builtin_elementwise_max(hA[k], (v2f){0.f, 0.f});
        hB[k] = __builtin_elementwise_max(hB[k], (v2f){0.f, 0.f});
      }
      #pragma unroll
      for (int m = 0; m < 6; ++m) {
        int kg = half*6 + m;           // global row pair: nodes 2kg, 2kg+1
        v2f hpA = hA[m], hpB = hB[m];
        v2f wcA0 = *(const v2f*)(Wc + ((2*kg)*32 + f0)*2);
        v2f wcA1 = *(const v2f*)(Wc + ((2*kg + 1)*32 + f0)*2);
        v2f wcB0 = *(const v2f*)(Wc + ((2*kg)*32 + f0 + 16)*2);
        v2f wcB1 = *(const v2f*)(Wc + ((2*kg + 1)*32 + f0 + 16)*2);
        p = pkfma_b0(wcA0, hpA, p);
        p = pkfma_b1(wcA1, hpA, p);
        p = pkfma_b0(wcB0, hpB, p);
        p = pkfma_b1(wcB1, hpB, p);
      }
    }
    float p0 = p.x, p1 = p.y;
    #pragma unroll
    for (int m = 1; m < 16; m <<= 1) {
      p0 += __shfl_xor(p0, m, 16);
      p1 += __shfl_xor(p1, m, 16);
    }
    if (f0 < 2) {
      float z0 = p0 + bc0, z1 = p1 + bc1;
      float mx = fmaxf(z0, z1);
      float lse = mx + logf(expf(z0 - mx) + expf(z1 - mx));
      int eg = blockIdx.x*EPB + e;
      out[eg*2 + f0] = (f0 == 0 ? z0 : z1) - lse;
    }
  }
}

extern "C" void kernel_launch(void* const* d_in, const int* in_sizes, int n_in,
                              void* d_out, int out_size, void* d_ws, size_t ws_size,
                              hipStream_t stream) {
  const float* x    = (const float*)d_in[0];
  const int*   ei   = (const int*)  d_in[1];
  const float* W1   = (const float*)d_in[2];  const float* b1 = (const float*)d_in[3];
  const float* W2   = (const float*)d_in[4];  const float* b2 = (const float*)d_in[5];
  const float* W3   = (const float*)d_in[6];  const float* b3 = (const float*)d_in[7];
  const float* W4   = (const float*)d_in[8];  const float* b4 = (const float*)d_in[9];
  const float* W5   = (const float*)d_in[10]; const float* b5 = (const float*)d_in[11];
  const float* W6   = (const float*)d_in[12]; const float* b6 = (const float*)d_in[13];
  const float* W7   = (const float*)d_in[14]; const float* b7 = (const float*)d_in[15];
  const float* fcw1 = (const float*)d_in[16]; const float* fcb1 = (const float*)d_in[17];
  const float* fcw2 = (const float*)d_in[18]; const float* fcb2 = (const float*)d_in[19];
  float* out = (float*)d_out;
  float* ws  = (float*)d_ws;
  int ec = in_sizes[1] / 2;        // 96 edges
  int B  = in_sizes[0] / NN;       // 32768

  hipLaunchKernelGGL(prep_kernel, dim3(9), dim3(T), 0, stream,
                     ei, ec, fcw1, fcb1, fcw2, fcb2, W7, ws);
  hipLaunchKernelGGL(gcn_main, dim3(B/EPB), dim3(T), 0, stream,
                     x, ws, W1,b1, W2,b2, W3,b3, W4,b4, W5,b5, W6,b6, W7,b7, out);
}

// Round 13
// 148.601 us; speedup vs baseline: 1.4852x; 1.0305x over previous
//
#include <hip/hip_runtime.h>
#include <math.h>

#define NN   24          // nodes per graph
#define EPB  16          // graph elements per block
#define CSTR 28          // LDS column stride (floats): 24 + 4 pad, 16B aligned
#define ESTR 452         // per-elem stride: 16*28 + 4 → e-stride ≡ 4 banks mod 32
#define T    256
#define AT_OFF  2176     // A^T (24x24) in ws, 16B-aligned float offset
#define W7T_OFF 2752     // W7 transposed [32][16] in ws

typedef float v2f __attribute__((ext_vector_type(2)));
typedef float v4f __attribute__((ext_vector_type(4)));

static __device__ __forceinline__ v2f vlo(v4f v){return __builtin_shufflevector(v,v,0,1);}
static __device__ __forceinline__ v2f vhi(v4f v){return __builtin_shufflevector(v,v,2,3);}

// Guaranteed packed math: d = a*b + c on 2xf32 register pairs.
static __device__ __forceinline__ v2f pkfma(v2f a, v2f b, v2f c) {
  asm("v_pk_fma_f32 %0, %1, %2, %0" : "+v"(c) : "v"(a), "v"(b));
  return c;
}
// c += a * broadcast(b.lo)  (src1 low half replicated via op_sel — no splat mov)
static __device__ __forceinline__ v2f pkfma_b0(v2f a, v2f b, v2f c) {
  asm("v_pk_fma_f32 %0, %1, %2, %0 op_sel:[0,0,0] op_sel_hi:[1,0,1]"
      : "+v"(c) : "v"(a), "v"(b));
  return c;
}
// c += a * broadcast(b.hi)
static __device__ __forceinline__ v2f pkfma_b1(v2f a, v2f b, v2f c) {
  asm("v_pk_fma_f32 %0, %1, %2, %0 op_sel:[0,1,0] op_sel_hi:[1,1,1]"
      : "+v"(c) : "v"(a), "v"(b));
  return c;
}
// Same, but a (src0) delivered from an SGPR pair — scalar-pipe operand flow.
static __device__ __forceinline__ v2f pkfma_sb0(v2f a, v2f b, v2f c) {
  asm("v_pk_fma_f32 %0, %1, %2, %0 op_sel:[0,0,0] op_sel_hi:[1,0,1]"
      : "+v"(c) : "s"(a), "v"(b));
  return c;
}
static __device__ __forceinline__ v2f pkfma_sb1(v2f a, v2f b, v2f c) {
  asm("v_pk_fma_f32 %0, %1, %2, %0 op_sel:[0,1,0] op_sel_hi:[1,1,1]"
      : "+v"(c) : "s"(a), "v"(b));
  return c;
}
// Multiplicative seeds: d = a * broadcast(b.lo) — replaces zero-init + fma.
static __device__ __forceinline__ v2f pkmul_b0(v2f a, v2f b) {
  v2f d;
  asm("v_pk_mul_f32 %0, %1, %2 op_sel:[0,0] op_sel_hi:[1,0]"
      : "=v"(d) : "v"(a), "v"(b));
  return d;
}
static __device__ __forceinline__ v2f pkmul_sb0(v2f a, v2f b) {
  v2f d;
  asm("v_pk_mul_f32 %0, %1, %2 op_sel:[0,0] op_sel_hi:[1,0]"
      : "=v"(d) : "s"(a), "v"(b));
  return d;
}

// ws layout (floats): [0..575] A(24x24) | [576..2111] Wc(768x2) | [2112..2113] bc(2)
//   | [2176..2751] AT(24x24) | [2752..3263] W7T(32x16)  (assumes ws_size >= 13056 B)

__global__ void prep_kernel(const int* __restrict__ ei, int ec,
                            const float* __restrict__ fcw1, const float* __restrict__ fcb1,
                            const float* __restrict__ fcw2, const float* __restrict__ fcb2,
                            const float* __restrict__ W7, float* __restrict__ ws) {
  int t = threadIdx.x;
  if (blockIdx.x == 0) {
    __shared__ float deg[NN];
    __shared__ float dinv[NN];
    __shared__ float As[NN*NN];
    __shared__ int s_is64;
    if (t == 0) s_is64 = 1;
    if (t < NN) deg[t] = 1.0f;            // self-loop contribution
    for (int k = t; k < NN*NN; k += T) As[k] = 0.0f;
    __syncthreads();
    // dtype sniff: int64 edge_index viewed as int32 has all odd (high) words == 0
    for (int k = t; k < 2*ec; k += T) {
      if (ei[2*k + 1] != 0) atomicExch(&s_is64, 0);
    }
    __syncthreads();
    int is64 = s_is64;
    for (int k = t; k < ec; k += T) {
      int d = is64 ? ei[2*(ec + k)] : ei[ec + k];
      atomicAdd(&deg[d], 1.0f);
    }
    __syncthreads();
    if (t < NN) dinv[t] = 1.0f / sqrtf(deg[t]);
    __syncthreads();
    for (int k = t; k < ec; k += T) {
      int s = is64 ? ei[2*k]        : ei[k];
      int d = is64 ? ei[2*(ec + k)] : ei[ec + k];
      atomicAdd(&As[d*NN + s], dinv[s]*dinv[d]);
    }
    if (t < NN) atomicAdd(&As[t*NN + t], dinv[t]*dinv[t]);  // self loop
    __syncthreads();
    for (int k = t; k < NN*NN; k += T) {
      float a = As[k];
      int r = k / NN, c = k % NN;
      ws[k] = a;                       // A (row-major), used by g1 stage
      ws[AT_OFF + c*NN + r] = a;       // A^T, used by column-form A-mix
    }
    // W7 transposed: W7T[f][fi] = W7[fi][f]  (pairs (fi,fi+1) become contiguous)
    for (int k = t; k < 512; k += T) {
      int f = k >> 4, fi = k & 15;
      ws[W7T_OFF + k] = W7[fi*32 + f];
    }
    // composed bias bc = fcb2 + fcb1 @ fcw2, wave-parallel (64 lanes + reduce)
    if (t < 64) {
      float p0 = 0.f, p1 = 0.f;
      #pragma unroll
      for (int k = t; k < 128; k += 64) {
        float b = fcb1[k];
        p0 += b*fcw2[k*2];
        p1 += b*fcw2[k*2 + 1];
      }
      #pragma unroll
      for (int m = 32; m; m >>= 1) {
        p0 += __shfl_down(p0, m, 64);
        p1 += __shfl_down(p1, m, 64);
      }
      if (t == 0) { ws[2112] = fcb2[0] + p0; ws[2113] = fcb2[1] + p1; }
    }
  } else {
    // Wc = fcw1 @ fcw2 : blocks 1..8 compute 96 rows each (fcw2 transposed in LDS)
    __shared__ __align__(16) float w2t[256];
    for (int k = t; k < 256; k += T) w2t[(k & 1)*128 + (k >> 1)] = fcw2[k];
    __syncthreads();
    int r0 = (blockIdx.x - 1) * 96;
    for (int idx = t; idx < 96*2; idx += T) {
      int r = r0 + (idx >> 1), c = idx & 1;
      const v4f* w1r = (const v4f*)(fcw1 + r*128);
      const v4f* w2v = (const v4f*)(w2t + c*128);
      v4f s = (v4f){0.f, 0.f, 0.f, 0.f};
      #pragma unroll
      for (int k = 0; k < 32; ++k) s = w1r[k]*w2v[k] + s;
      ws[576 + r*2 + c] = (s.x + s.y) + (s.z + s.w);
    }
  }
}

// Merged step (L1-L4): W-mix h col f in 12 v2f via op_sel-broadcast pk-fma with
// TRANSPOSED PADDED weights ([FOUT][ST] in LDS, ST non-pow2 → f*ST hits all
// distinct banks — conflict-free weight-pair loads). Barrier, then column-form
// A-mix with A operands via scalar pipe, pk_mul-seeded.
template<int FIN, int FOUT, int SPLIT, int ST>
__device__ __forceinline__ void merged_layer(const float* __restrict__ ATg, float* gbuf,
                                             const float* Ws, const float* bs, int t) {
  constexpr int NCOLS = EPB*FOUT;       // 64/64/128/128
  constexpr int CL    = NN/SPLIT;       // 6/6/12/12
  constexpr int NV    = CL/2;
  int col = t & (NCOLS - 1);
  int i0  = __builtin_amdgcn_readfirstlane((t / NCOLS) * CL);  // wave-uniform
  int e = col / FOUT;
  int f = col & (FOUT - 1);
  const float* ib = gbuf + e*ESTR;
  float bf = bs[f];
  v2f hh[12];
  #pragma unroll
  for (int k = 0; k < 12; ++k) hh[k] = (v2f){bf, bf};
  if constexpr (FIN == 1) {
    float w = Ws[f];                    // [FOUT][1] transposed == linear
    v2f w2 = (v2f){w, w};
    const v4f* c4 = (const v4f*)ib;
    #pragma unroll
    for (int k = 0; k < 6; ++k) {
      v4f v = c4[k];
      hh[2*k]   = pkfma(vlo(v), w2, hh[2*k]);
      hh[2*k+1] = pkfma(vhi(v), w2, hh[2*k+1]);
    }
  } else {
    #pragma unroll
    for (int fp = 0; fp < FIN/2; ++fp) {
      v2f wp = *(const v2f*)(Ws + f*ST + 2*fp);   // (w[2fp], w[2fp+1])
      const v4f* cA = (const v4f*)(ib + (2*fp)*CSTR);
      const v4f* cB = (const v4f*)(ib + (2*fp+1)*CSTR);
      #pragma unroll
      for (int k = 0; k < 6; ++k) {
        v4f vA = cA[k], vB = cB[k];
        hh[2*k]   = pkfma_b0(vlo(vA), wp, hh[2*k]);
        hh[2*k+1] = pkfma_b0(vhi(vA), wp, hh[2*k+1]);
        hh[2*k]   = pkfma_b1(vlo(vB), wp, hh[2*k]);
        hh[2*k+1] = pkfma_b1(vhi(vB), wp, hh[2*k+1]);
      }
    }
  }
  #pragma unroll
  for (int k = 0; k < 12; ++k)
    hh[k] = __builtin_elementwise_max(hh[k], (v2f){0.f, 0.f});
  __syncthreads();           // all gbuf reads complete before in-place overwrite
  // A-mix, column form over rows i0..i0+CL-1; jp runs over h pairs; mul seed.
  float* ob = gbuf + e*ESTR + f*CSTR + i0;
  v2f acc[NV];
  {
    v2f hp = hh[0];
    const v2f* gA = (const v2f*)(ATg + i0);
    const v2f* gB = (const v2f*)(ATg + NN + i0);
    #pragma unroll
    for (int k = 0; k < NV; ++k) {
      acc[k] = pkmul_sb0(gA[k], hp);
      acc[k] = pkfma_sb1(gB[k], hp, acc[k]);
    }
  }
  #pragma unroll
  for (int jp = 1; jp < 12; ++jp) {
    v2f hp = hh[jp];
    const v2f* gA = (const v2f*)(ATg + (2*jp)*NN + i0);      // uniform → s_load
    const v2f* gB = (const v2f*)(ATg + (2*jp + 1)*NN + i0);
    #pragma unroll
    for (int k = 0; k < NV; ++k) {
      acc[k] = pkfma_sb0(gA[k], hp, acc[k]);
      acc[k] = pkfma_sb1(gB[k], hp, acc[k]);
    }
  }
  #pragma unroll
  for (int k = 0; k < NV; ++k) *(v2f*)(ob + 2*k) = acc[k];
}

// L5/L6 (FOUT=16) with fi-SPLIT LANE PAIRING + transposed padded weights +
// pk_mul seeds. Lanes (l, l+32) serve the same (e, f-pair); each sums its
// fi-half for both columns; h = pA + shfl_xor(pB, 32).
template<int FIN, int ST>
__device__ __forceinline__ void fused16s(const float* __restrict__ ATg, float* gbuf,
                                         const float* Ws, const float* bs, int t) {
  int lane = t & 63, w = t >> 6;
  int q = w*32 + (lane & 31);           // pair index: 32 pairs/wave, 128 total
  int e = q >> 3, f_lo = q & 7;
  int hi = lane >> 5;                   // 0 = lo half, 1 = hi half
  int fcol = f_lo + (hi << 3);          // own output column
  int fother = f_lo + ((1 - hi) << 3);  // partner's column
  int fib = hi * (FIN/2);               // own fi range base
  const float* ib = gbuf + e*ESTR;
  float bf = bs[fcol];
  v2f pA[12], pB[12];
  #pragma unroll
  for (int k = 0; k < 12; ++k) pA[k] = (v2f){bf, bf};
  // fp = 0: pB seeded by pk_mul (no zero-init)
  {
    int fe = fib;
    v2f wpA = *(const v2f*)(Ws + fcol*ST + fe);
    v2f wpB = *(const v2f*)(Ws + fother*ST + fe);
    const v4f* cA = (const v4f*)(ib + fe*CSTR);
    const v4f* cB = (const v4f*)(ib + (fe+1)*CSTR);
    #pragma unroll
    for (int k = 0; k < 6; ++k) {
      v4f vA = cA[k], vB = cB[k];
      v2f alo = vlo(vA), ahi = vhi(vA), blo = vlo(vB), bhi = vhi(vB);
      pA[2*k]   = pkfma_b0(alo, wpA, pA[2*k]);
      pA[2*k+1] = pkfma_b0(ahi, wpA, pA[2*k+1]);
      pB[2*k]   = pkmul_b0(alo, wpB);
      pB[2*k+1] = pkmul_b0(ahi, wpB);
      pA[2*k]   = pkfma_b1(blo, wpA, pA[2*k]);
      pA[2*k+1] = pkfma_b1(bhi, wpA, pA[2*k+1]);
      pB[2*k]   = pkfma_b1(blo, wpB, pB[2*k]);
      pB[2*k+1] = pkfma_b1(bhi, wpB, pB[2*k+1]);
    }
  }
  #pragma unroll
  for (int fp = 1; fp < FIN/4; ++fp) {
    int fe = 2*fp + fib;
    v2f wpA = *(const v2f*)(Ws + fcol*ST + fe);
    v2f wpB = *(const v2f*)(Ws + fother*ST + fe);
    const v4f* cA = (const v4f*)(ib + fe*CSTR);
    const v4f* cB = (const v4f*)(ib + (fe+1)*CSTR);
    #pragma unroll
    for (int k = 0; k < 6; ++k) {
      v4f vA = cA[k], vB = cB[k];
      v2f alo = vlo(vA), ahi = vhi(vA), blo = vlo(vB), bhi = vhi(vB);
      pA[2*k]   = pkfma_b0(alo, wpA, pA[2*k]);
      pA[2*k+1] = pkfma_b0(ahi, wpA, pA[2*k+1]);
      pB[2*k]   = pkfma_b0(alo, wpB, pB[2*k]);
      pB[2*k+1] = pkfma_b0(ahi, wpB, pB[2*k+1]);
      pA[2*k]   = pkfma_b1(blo, wpA, pA[2*k]);
      pA[2*k+1] = pkfma_b1(bhi, wpA, pA[2*k+1]);
      pB[2*k]   = pkfma_b1(blo, wpB, pB[2*k]);
      pB[2*k+1] = pkfma_b1(bhi, wpB, pB[2*k+1]);
    }
  }
  // cross-lane completion: partner's pB is the missing fi-half of my column
  v2f h[12];
  #pragma unroll
  for (int k = 0; k < 12; ++k) {
    v2f r;
    r.x = __shfl_xor(pB[k].x, 32);
    r.y = __shfl_xor(pB[k].y, 32);
    h[k] = __builtin_elementwise_max(pA[k] + r, (v2f){0.f, 0.f});
  }
  __syncthreads();           // all gbuf reads complete before in-place overwrite
  // A-mix, full column (i0 = 0, CL = 24), scalar-pipe A operands, mul seed
  float* ob = gbuf + e*ESTR + fcol*CSTR;
  v2f acc[12];
  {
    v2f hp = h[0];
    const v2f* gA = (const v2f*)(ATg);
    const v2f* gB = (const v2f*)(ATg + NN);
    #pragma unroll
    for (int k = 0; k < 12; ++k) {
      acc[k] = pkmul_sb0(gA[k], hp);
      acc[k] = pkfma_sb1(gB[k], hp, acc[k]);
    }
  }
  #pragma unroll
  for (int jp = 1; jp < 12; ++jp) {
    v2f hp = h[jp];
    const v2f* gA = (const v2f*)(ATg + (2*jp)*NN);           // uniform → s_load
    const v2f* gB = (const v2f*)(ATg + (2*jp + 1)*NN);
    #pragma unroll
    for (int k = 0; k < 12; ++k) {
      acc[k] = pkfma_sb0(gA[k], hp, acc[k]);
      acc[k] = pkfma_sb1(gB[k], hp, acc[k]);
    }
  }
  #pragma unroll
  for (int k = 0; k < 12; ++k) *(v2f*)(ob + 2*k) = acc[k];
}

__global__ __launch_bounds__(256, 4) void gcn_main(
    const float* __restrict__ x, const float* __restrict__ ws,
    const float* __restrict__ W1, const float* __restrict__ b1,
    const float* __restrict__ W2, const float* __restrict__ b2,
    const float* __restrict__ W3, const float* __restrict__ b3,
    const float* __restrict__ W4, const float* __restrict__ b4,
    const float* __restrict__ W5, const float* __restrict__ b5,
    const float* __restrict__ W6, const float* __restrict__ b6,
    const float* __restrict__ W7, const float* __restrict__ b7,
    float* __restrict__ out) {
  __shared__ __align__(16) float gbuf[EPB*ESTR];  // 28928 B, single in-place buffer
  __shared__ float Wsh[604];          // W1..W6 transposed, PADDED strides
  __shared__ __align__(16) float bsh[88];
  int t = threadIdx.x;
  const float* ATg = ws + AT_OFF;       // wave-uniform: scalar-pipe delivery

  // stage layer weights (transposed, padded stride) / biases into LDS
  {
    const float* Wp[6] = {W1,W2,W3,W4,W5,W6};
    const float* bp[7] = {b1,b2,b3,b4,b5,b6,b7};
    const int wsz[6]   = {4,16,32,64,128,256};
    const int wof[6]   = {0,4,28,76,156,316};   // padded offsets (all even)
    const int fouts[6] = {4,4,8,8,16,16};
    const int wst[6]   = {1,6,6,10,10,18};      // padded strides (non-pow2)
    const int bsz[7] = {4,4,8,8,16,16,32};
    const int bof[7] = {0,4,8,16,24,40,56};
    #pragma unroll
    for (int l = 0; l < 6; ++l) {
      int FO = fouts[l], ST = wst[l];
      for (int k = t; k < wsz[l]; k += T) {
        int fi = k / FO, f = k - fi*FO;
        Wsh[wof[l] + f*ST + fi] = Wp[l][k];
      }
    }
    #pragma unroll
    for (int l = 0; l < 7; ++l) {
      if (t < bsz[l]) bsh[bof[l] + t] = bp[l][t];
    }
  }
  // stage x tile into column slot 1 of each elem (col 0 gets g1 = A@x)
  {
    const float* xg = x + (size_t)blockIdx.x * (EPB*NN);
    if (t < EPB*NN/4) {
      float4 v = ((const float4*)xg)[t];
      int e = t/6, k = t - e*6;
      ((float4*)(gbuf + e*ESTR + CSTR))[k] = v;
    }
  }
  __syncthreads();

  // g1 = A @ x : 384 tasks (e, i); A rows per-lane from global (2.3 KB, L1-hot)
  {
    int e = t & 15, i = t >> 4;          // i in 0..15
    const float4* xv = (const float4*)(gbuf + e*ESTR + CSTR);
    const float4* Ar = (const float4*)(ws + i*NN);
    float acc = 0.f;
    #pragma unroll
    for (int k = 0; k < 6; ++k) {
      float4 a = Ar[k]; float4 v = xv[k];
      acc += a.x*v.x + a.y*v.y + a.z*v.z + a.w*v.w;
    }
    gbuf[e*ESTR + i] = acc;
    if (t < 128) {
      int i2 = 16 + (t >> 4);            // i in 16..23
      const float4* Ar2 = (const float4*)(ws + i2*NN);
      float acc2 = 0.f;
      #pragma unroll
      for (int k = 0; k < 6; ++k) {
        float4 a = Ar2[k]; float4 v = xv[k];
        acc2 += a.x*v.x + a.y*v.y + a.z*v.z + a.w*v.w;
      }
      gbuf[e*ESTR + i2] = acc2;
    }
  }
  __syncthreads();

  merged_layer<1, 4, 4, 1>(ATg, gbuf, Wsh+0,   bsh+0,  t); __syncthreads();
  merged_layer<4, 4, 4, 6>(ATg, gbuf, Wsh+4,   bsh+4,  t); __syncthreads();
  merged_layer<4, 8, 2, 6>(ATg, gbuf, Wsh+28,  bsh+8,  t); __syncthreads();
  merged_layer<8, 8, 2,10>(ATg, gbuf, Wsh+76,  bsh+16, t); __syncthreads();
  fused16s<8, 10>(ATg, gbuf, Wsh+156, bsh+24, t);          __syncthreads();
  fused16s<16,18>(ATg, gbuf, Wsh+316, bsh+40, t);          __syncthreads();

  // L7 + composed FC + log_softmax, READ-ONCE 2-col form with row-half passes
  // and TRANSPOSED W7 (pairs → op_sel broadcast, zero splats).
  {
    const float* Wc  = ws + 576;
    const float* W7T = ws + W7T_OFF;     // [32][16]
    float bc0 = ws[2112], bc1 = ws[2113];
    int e = t >> 4, f0 = t & 15;
    const float* ib = gbuf + e*ESTR;
    float bA = bsh[56 + f0], bB = bsh[56 + f0 + 16];
    v2f p = (v2f){0.f, 0.f};           // (p0, p1)
    #pragma unroll
    for (int half = 0; half < 2; ++half) {
      v2f hA[6], hB[6];
      #pragma unroll
      for (int k = 0; k < 6; ++k) { hA[k] = (v2f){bA, bA}; hB[k] = (v2f){bB, bB}; }
      #pragma unroll
      for (int fp = 0; fp < 8; ++fp) {
        v2f wpA = *(const v2f*)(W7T + f0*16 + 2*fp);        // L1-cached
        v2f wpB = *(const v2f*)(W7T + (f0 + 16)*16 + 2*fp);
        const v4f* cA = (const v4f*)(ib + (2*fp)*CSTR + half*12);
        const v4f* cB = (const v4f*)(ib + (2*fp+1)*CSTR + half*12);
        #pragma unroll
        for (int k = 0; k < 3; ++k) {
          v4f vA = cA[k], vB = cB[k];
          v2f alo = vlo(vA), ahi = vhi(vA), blo = vlo(vB), bhi = vhi(vB);
          hA[2*k]   = pkfma_b0(alo, wpA, hA[2*k]);
          hA[2*k+1] = pkfma_b0(ahi, wpA, hA[2*k+1]);
          hB[2*k]   = pkfma_b0(alo, wpB, hB[2*k]);
          hB[2*k+1] = pkfma_b0(ahi, wpB, hB[2*k+1]);
          hA[2*k]   = pkfma_b1(blo, wpA, hA[2*k]);
          hA[2*k+1] = pkfma_b1(bhi, wpA, hA[2*k+1]);
          hB[2*k]   = pkfma_b1(blo, wpB, hB[2*k]);
          hB[2*k+1] = pkfma_b1(bhi, wpB, hB[2*k+1]);
        }
      }
      #pragma unroll
      for (int k = 0; k < 6; ++k) {
        hA[k] = __builtin_elementwise_max(hA[k], (v2f){0.f, 0.f});
        hB[k] = __builtin_elementwise_max(hB[k], (v2f){0.f, 0.f});
      }
      #pragma unroll
      for (int m = 0; m < 6; ++m) {
        int kg = half*6 + m;           // global row pair: nodes 2kg, 2kg+1
        v2f hpA = hA[m], hpB = hB[m];
        v2f wcA0 = *(const v2f*)(Wc + ((2*kg)*32 + f0)*2);
        v2f wcA1 = *(const v2f*)(Wc + ((2*kg + 1)*32 + f0)*2);
        v2f wcB0 = *(const v2f*)(Wc + ((2*kg)*32 + f0 + 16)*2);
        v2f wcB1 = *(const v2f*)(Wc + ((2*kg + 1)*32 + f0 + 16)*2);
        p = pkfma_b0(wcA0, hpA, p);
        p = pkfma_b1(wcA1, hpA, p);
        p = pkfma_b0(wcB0, hpB, p);
        p = pkfma_b1(wcB1, hpB, p);
      }
    }
    float p0 = p.x, p1 = p.y;
    #pragma unroll
    for (int m = 1; m < 16; m <<= 1) {
      p0 += __shfl_xor(p0, m, 16);
      p1 += __shfl_xor(p1, m, 16);
    }
    if (f0 < 2) {
      float z0 = p0 + bc0, z1 = p1 + bc1;
      float mx = fmaxf(z0, z1);
      float lse = mx + logf(expf(z0 - mx) + expf(z1 - mx));
      int eg = blockIdx.x*EPB + e;
      out[eg*2 + f0] = (f0 == 0 ? z0 : z1) - lse;
    }
  }
}

extern "C" void kernel_launch(void* const* d_in, const int* in_sizes, int n_in,
                              void* d_out, int out_size, void* d_ws, size_t ws_size,
                              hipStream_t stream) {
  const float* x    = (const float*)d_in[0];
  const int*   ei   = (const int*)  d_in[1];
  const float* W1   = (const float*)d_in[2];  const float* b1 = (const float*)d_in[3];
  const float* W2   = (const float*)d_in[4];  const float* b2 = (const float*)d_in[5];
  const float* W3   = (const float*)d_in[6];  const float* b3 = (const float*)d_in[7];
  const float* W4   = (const float*)d_in[8];  const float* b4 = (const float*)d_in[9];
  const float* W5   = (const float*)d_in[10]; const float* b5 = (const float*)d_in[11];
  const float* W6   = (const float*)d_in[12]; const float* b6 = (const float*)d_in[13];
  const float* W7   = (const float*)d_in[14]; const float* b7 = (const float*)d_in[15];
  const float* fcw1 = (const float*)d_in[16]; const float* fcb1 = (const float*)d_in[17];
  const float* fcw2 = (const float*)d_in[18]; const float* fcb2 = (const float*)d_in[19];
  float* out = (float*)d_out;
  float* ws  = (float*)d_ws;
  int ec = in_sizes[1] / 2;        // 96 edges
  int B  = in_sizes[0] / NN;       // 32768

  hipLaunchKernelGGL(prep_kernel, dim3(9), dim3(T), 0, stream,
                     ei, ec, fcw1, fcb1, fcw2, fcb2, W7, ws);
  hipLaunchKernelGGL(gcn_main, dim3(B/EPB), dim3(T), 0, stream,
                     x, ws, W1,b1, W2,b2, W3,b3, W4,b4, W5,b5, W6,b6, W7,b7, out);
}